// Round 14
// baseline (1713.279 us; speedup 1.0000x reference)
//
#include <hip/hip_runtime.h>
#include <hip/hip_bf16.h>
#include <math.h>

#define L_LAYERS 8
#define DIM 1024
#define NH 16
#define HD 64
#define HID 4096
#define VOCAB 32000
#define BB 2
#define TT 1024
#define MROWS (BB*TT)

typedef unsigned short u16;
typedef short short8 __attribute__((ext_vector_type(8)));
typedef float f32x4 __attribute__((ext_vector_type(4)));
typedef unsigned short us4 __attribute__((ext_vector_type(4)));
typedef unsigned short us8 __attribute__((ext_vector_type(8)));

__device__ __forceinline__ float bf2f(u16 x){
  union { unsigned int u; float f; } v; v.u = ((unsigned int)x) << 16; return v.f;
}
__device__ __forceinline__ u16 f2bf(float f){
  union { float f; unsigned int u; } v; v.f = f;
  unsigned int r = (v.u + 0x7fffu + ((v.u >> 16) & 1u)) >> 16; return (u16)r;
}

#define AS1 __attribute__((address_space(1)))
#define AS3 __attribute__((address_space(3)))
__device__ __forceinline__ void gld_lds16(const void* g, void* l){
  __builtin_amdgcn_global_load_lds((const AS1 void*)g, (AS3 void*)l, 16, 0, 0);
}

// ---------------- embedding ----------------
__global__ void k_embed(const int* __restrict__ ids, const float* __restrict__ Wemb,
                        float* __restrict__ h, u16* __restrict__ hb){
  int bt = blockIdx.x; long id = ids[bt];
  const float4* src = (const float4*)(Wemb + id*(long)DIM);
  float4 v = src[threadIdx.x];
  ((float4*)(h + (long)bt*DIM))[threadIdx.x] = v;
  us4 o = { f2bf(v.x), f2bf(v.y), f2bf(v.z), f2bf(v.w) };
  ((us4*)(hb + (long)bt*DIM))[threadIdx.x] = o;
}

// ---------------- f32 -> bf16 elementwise (Wemb) ----------------
__global__ void k_cvt(const float* __restrict__ src, u16* __restrict__ dst, long n){
  long i = ((long)blockIdx.x*256 + threadIdx.x)*8;
  if (i >= n) return;
  float4 a = ((const float4*)(src+i))[0];
  float4 b = ((const float4*)(src+i))[1];
  us4 o0 = { f2bf(a.x), f2bf(a.y), f2bf(a.z), f2bf(a.w) };
  us4 o1 = { f2bf(b.x), f2bf(b.y), f2bf(b.z), f2bf(b.w) };
  ((us4*)(dst+i))[0] = o0; ((us4*)(dst+i))[1] = o1;
}

// ---------------- per-layer weight convert + transpose (coalesced both sides) ----------------
__global__ void k_cvt_layer(const float* __restrict__ Wq, const float* __restrict__ Wk,
    const float* __restrict__ Wv, const float* __restrict__ Wo,
    const float* __restrict__ Wfc, const float* __restrict__ Wg, const float* __restrict__ Wp,
    u16* __restrict__ qkvT, u16* __restrict__ woT, u16* __restrict__ fgT, u16* __restrict__ projT)
{
  int tile = blockIdx.x;
  const float* src; u16* dst; int R, C, tr, tc;
  long rowmul = 1, rowoff = 0;
  if (tile < 1024){
    int m = tile >> 8, t2 = tile & 255;
    tr = t2 >> 4; tc = t2 & 15; R = 1024; C = 1024;
    src = (m==0)?Wq:(m==1)?Wk:(m==2)?Wv:Wo;
    dst = (m<3)? qkvT + (long)m*1024*1024 : woT;
  } else if (tile < 3072){
    int m = (tile - 1024) >> 10, t2 = (tile - 1024) & 1023;
    tr = t2 >> 6; tc = t2 & 63; R = 1024; C = 4096;
    src = m ? Wg : Wfc; dst = fgT; rowmul = 2; rowoff = m;
  } else {
    int t2 = tile - 3072;
    tr = t2 >> 4; tc = t2 & 15; R = 4096; C = 1024;
    src = Wp; dst = projT;
  }
  __shared__ float ls[64][65];
  int u = threadIdx.x;
  int rr16 = u >> 4;
  int cu   = u & 15;
  #pragma unroll
  for (int p = 0; p < 4; ++p){
    int r = p*16 + rr16;
    float4 v = *(const float4*)(src + (long)(tr*64 + r)*C + tc*64 + cu*4);
    ls[r][cu*4+0]=v.x; ls[r][cu*4+1]=v.y; ls[r][cu*4+2]=v.z; ls[r][cu*4+3]=v.w;
  }
  __syncthreads();
  int d  = u >> 2;
  int c4 = u & 3;
  long drow = (long)tc*64 + d;
  u16* dp = dst + (drow*rowmul + rowoff)*R + tr*64;
  #pragma unroll
  for (int g2 = 0; g2 < 2; ++g2){
    int e0 = (c4 + g2*4) * 8;
    us8 o;
    #pragma unroll
    for (int j=0;j<8;j++) o[j] = f2bf(ls[e0+j][d]);
    *((us8*)(dp + e0)) = o;
  }
}

// ============ 128-tile bf16 GEMM (qkv / wo-splitK / proj-splitK) ============
template<int EPI>
__global__ __launch_bounds__(256, 2) void k_gemm(
    const u16* __restrict__ A, long lda,
    const u16* __restrict__ Bt, long ldb,
    void* __restrict__ Cp, long ldc,
    int K, int nMt, float alpha, int ksplit,
    u16* __restrict__ hbout)
{
  __shared__ u16 lsA[128*32];
  __shared__ u16 lsB[128*32];
  int nflat = gridDim.x; int w = blockIdx.x;
  if ((nflat & 7) == 0){ int q = nflat >> 3; w = (w & 7)*q + (w >> 3); }
  int perk = nflat / ksplit;
  int kc = w / perk; int w2 = w - kc*perk;
  int mtile = w2 % nMt, ntile = w2 / nMt;
  const u16* Ab = A + (long)mtile*128*lda + (long)kc*K;
  const u16* Bb = Bt + (long)ntile*128*ldb + (long)kc*K;
  int t = threadIdx.x;
  int wv = t >> 6, ln = t & 63;
  int srow = t >> 2;
  int scol = (t & 3) * 8;
  int fr = ln & 15, kg = ln >> 4;
  int wr = wv >> 1, wc = wv & 1;
  const f32x4 zero = {0.f,0.f,0.f,0.f};
  f32x4 acc[4][4];
  #pragma unroll
  for (int m=0;m<4;m++)
    #pragma unroll
    for (int n=0;n<4;n++) acc[m][n] = zero;
  const u16* ga0 = Ab + (long)srow*lda + scol;
  const u16* ga1 = Ab + (long)(srow+64)*lda + scol;
  const u16* gb0 = Bb + (long)srow*ldb + scol;
  const u16* gb1 = Bb + (long)(srow+64)*ldb + scol;
  u16* la0 = lsA + wv*512;
  u16* la1 = lsA + 2048 + wv*512;
  u16* lb0 = lsB + wv*512;
  u16* lb1 = lsB + 2048 + wv*512;
  for (int k0 = 0; k0 < K; k0 += 32){
    gld_lds16(ga0 + k0, la0);
    gld_lds16(ga1 + k0, la1);
    gld_lds16(gb0 + k0, lb0);
    gld_lds16(gb1 + k0, lb1);
    __syncthreads();
    short8 af[4], bfr[4];
    #pragma unroll
    for (int m=0;m<4;m++) af[m]  = *(const short8*)(lsA + (wr*64 + m*16 + fr)*32 + kg*8);
    #pragma unroll
    for (int n=0;n<4;n++) bfr[n] = *(const short8*)(lsB + (wc*64 + n*16 + fr)*32 + kg*8);
    #pragma unroll
    for (int m=0;m<4;m++)
      #pragma unroll
      for (int n=0;n<4;n++)
        acc[m][n] = __builtin_amdgcn_mfma_f32_16x16x32_bf16(af[m], bfr[n], acc[m][n], 0, 0, 0);
    __syncthreads();
  }
  long row0 = (long)mtile*128 + wr*64 + kg*4;
  int col0 = ntile*128 + wc*64 + fr;
  if constexpr (EPI == 0){
    u16* C = (u16*)Cp;
    #pragma unroll
    for (int m=0;m<4;m++)
      #pragma unroll
      for (int r=0;r<4;r++){
        long row = row0 + m*16 + r;
        #pragma unroll
        for (int n=0;n<4;n++) C[row*ldc + col0 + n*16] = f2bf(acc[m][n][r]);
      }
  } else if constexpr (EPI == 2){
    float* C = (float*)Cp;
    #pragma unroll
    for (int m=0;m<4;m++)
      #pragma unroll
      for (int r=0;r<4;r++){
        long row = row0 + m*16 + r;
        #pragma unroll
        for (int n=0;n<4;n++){
          long idx = row*ldc + col0 + n*16;
          float v = C[idx] + acc[m][n][r]*alpha;
          C[idx] = v;
          hbout[idx] = f2bf(v);
        }
      }
  } else { // EPI 5
    float* C = (float*)Cp + (long)kc*MROWS*ldc;
    #pragma unroll
    for (int m=0;m<4;m++)
      #pragma unroll
      for (int r=0;r<4;r++){
        long row = row0 + m*16 + r;
        #pragma unroll
        for (int n=0;n<4;n++) C[row*ldc + col0 + n*16] = acc[m][n][r];
      }
  }
}

// ---------------- split-K reduce (NS partials) + residual ----------------
template<int NS>
__global__ void k_redKn(const float* __restrict__ pK, float* __restrict__ h, u16* __restrict__ hb){
  long idx = ((long)blockIdx.x*256 + threadIdx.x)*4;
  const float aL = 0.35355339059327373f;
  float4 s = *(const float4*)(pK + idx);
  #pragma unroll
  for (int j=1;j<NS;j++){
    float4 sj = *(const float4*)(pK + idx + (long)j*MROWS*1024);
    s.x += sj.x; s.y += sj.y; s.z += sj.z; s.w += sj.w;
  }
  float4 hv = *(const float4*)(h + idx);
  float4 v;
  v.x = hv.x + s.x*aL;
  v.y = hv.y + s.y*aL;
  v.z = hv.z + s.z*aL;
  v.w = hv.w + s.w*aL;
  *(float4*)(h + idx) = v;
  us4 o = { f2bf(v.x), f2bf(v.y), f2bf(v.z), f2bf(v.w) };
  *(us4*)(hb + idx) = o;
}

// ============ 256x256 8-wave BK=64 GEMM, 2-phase + register-reuse (fg / lm_head) ============
// XCD-resident A mapping: nMt == 8 == #XCDs; each XCD chunk owns ONE m-tile (A-panel 0.5MB
// stays L2-resident) and streams its ntile range once -> minimal L2-miss traffic.
#define MFMA_(va,vb,vc) __builtin_amdgcn_mfma_f32_16x16x32_bf16(va,vb,vc,0,0,0)
#define RD2(base, row, ku) (*(const short8*)((base) + (row)*64 + ((((ku) ^ ((row)&7)))<<3)))

template<int EPI>
__global__ __launch_bounds__(512, 1) void k_gemm256(
    const u16* __restrict__ A, long lda,
    const u16* __restrict__ Bt, long ldb,
    void* __restrict__ Cp, long ldc,
    int K, int nMt,
    float2* __restrict__ partials)
{
  __shared__ u16 lds[65536];   // [A0 32KB][B0 32KB][A1 32KB][B1 32KB]
  int nwg = gridDim.x; int w = blockIdx.x;
  { int q = nwg >> 3, r8 = nwg & 7; int xcd = w & 7, lw = w >> 3;
    w = (xcd < r8 ? xcd*(q+1) : r8*(q+1) + (xcd-r8)*q) + lw; }
  int nNt = nwg / nMt;
  int ntile = w % nNt, mtile = w / nNt;   // n fastest: XCD chunk = one m-tile
  const u16* Abase = A + (long)mtile*256*lda;
  const u16* Bbase = Bt + (long)ntile*256*ldb;
  int tid = threadIdx.x;
  int wid = tid >> 6, ln = tid & 63;
  int wm = wid >> 2, wn = wid & 3;
  int fr = ln & 15, kg = ln >> 4;

  f32x4 acc[8][4];
  #pragma unroll
  for (int a=0;a<8;a++)
    #pragma unroll
    for (int b=0;b<4;b++) acc[a][b] = (f32x4){0.f,0.f,0.f,0.f};

#define STAGE_A(i, kofs, dstbase) do{ \
    int u_ = (i)*512 + tid; int r_ = u_>>3; int cu_ = u_&7; \
    gld_lds16(Abase + (long)r_*lda + (kofs) + ((cu_^(r_&7))<<3), \
              (dstbase) + (((i)*512 + wid*64)<<3)); }while(0)
#define STAGE_B(i, kofs, dstbase) do{ \
    int u_ = (i)*512 + tid; int r_ = u_>>3; int cu_ = u_&7; \
    gld_lds16(Bbase + (long)r_*ldb + (kofs) + ((cu_^(r_&7))<<3), \
              (dstbase) + (((i)*512 + wid*64)<<3)); }while(0)

#define KHALF(ks) do{ \
    short8 a0 = RD2(ldsA, wm*128 +   0 + fr, (ks)*4+kg); \
    short8 a1 = RD2(ldsA, wm*128 +  16 + fr, (ks)*4+kg); \
    short8 a2 = RD2(ldsA, wm*128 +  32 + fr, (ks)*4+kg); \
    short8 a3 = RD2(ldsA, wm*128 +  48 + fr, (ks)*4+kg); \
    short8 a4 = RD2(ldsA, wm*128 +  64 + fr, (ks)*4+kg); \
    short8 a5 = RD2(ldsA, wm*128 +  80 + fr, (ks)*4+kg); \
    short8 a6 = RD2(ldsA, wm*128 +  96 + fr, (ks)*4+kg); \
    short8 a7 = RD2(ldsA, wm*128 + 112 + fr, (ks)*4+kg); \
    short8 b0 = RD2(ldsB, wn*64 +  0 + fr, (ks)*4+kg); \
    short8 b1 = RD2(ldsB, wn*64 + 16 + fr, (ks)*4+kg); \
    short8 b2 = RD2(ldsB, wn*64 + 32 + fr, (ks)*4+kg); \
    short8 b3 = RD2(ldsB, wn*64 + 48 + fr, (ks)*4+kg); \
    acc[0][0]=MFMA_(a0,b0,acc[0][0]); acc[1][0]=MFMA_(a1,b0,acc[1][0]); \
    acc[0][1]=MFMA_(a0,b1,acc[0][1]); acc[1][1]=MFMA_(a1,b1,acc[1][1]); \
    acc[2][0]=MFMA_(a2,b0,acc[2][0]); acc[3][0]=MFMA_(a3,b0,acc[3][0]); \
    acc[2][1]=MFMA_(a2,b1,acc[2][1]); acc[3][1]=MFMA_(a3,b1,acc[3][1]); \
    acc[0][2]=MFMA_(a0,b2,acc[0][2]); acc[1][2]=MFMA_(a1,b2,acc[1][2]); \
    acc[0][3]=MFMA_(a0,b3,acc[0][3]); acc[1][3]=MFMA_(a1,b3,acc[1][3]); \
    acc[2][2]=MFMA_(a2,b2,acc[2][2]); acc[3][2]=MFMA_(a3,b2,acc[3][2]); \
    acc[2][3]=MFMA_(a2,b3,acc[2][3]); acc[3][3]=MFMA_(a3,b3,acc[3][3]); \
    acc[4][0]=MFMA_(a4,b0,acc[4][0]); acc[5][0]=MFMA_(a5,b0,acc[5][0]); \
    acc[4][1]=MFMA_(a4,b1,acc[4][1]); acc[5][1]=MFMA_(a5,b1,acc[5][1]); \
    acc[6][0]=MFMA_(a6,b0,acc[6][0]); acc[7][0]=MFMA_(a7,b0,acc[7][0]); \
    acc[6][1]=MFMA_(a6,b1,acc[6][1]); acc[7][1]=MFMA_(a7,b1,acc[7][1]); \
    acc[4][2]=MFMA_(a4,b2,acc[4][2]); acc[5][2]=MFMA_(a5,b2,acc[5][2]); \
    acc[4][3]=MFMA_(a4,b3,acc[4][3]); acc[5][3]=MFMA_(a5,b3,acc[5][3]); \
    acc[6][2]=MFMA_(a6,b2,acc[6][2]); acc[7][2]=MFMA_(a7,b2,acc[7][2]); \
    acc[6][3]=MFMA_(a6,b3,acc[6][3]); acc[7][3]=MFMA_(a7,b3,acc[7][3]); \
  }while(0)

  // prologue: stage tile 0 into buffer 0
  {
    u16* dA = lds; u16* dB = lds + 16384;
    STAGE_A(0, 0, dA); STAGE_A(1, 0, dA); STAGE_A(2, 0, dA); STAGE_A(3, 0, dA);
    STAGE_B(0, 0, dB); STAGE_B(1, 0, dB); STAGE_B(2, 0, dB); STAGE_B(3, 0, dB);
  }
  const int NT = K >> 6;
  #pragma unroll 2
  for (int jt = 0; jt < NT; ++jt){
    int bsel = jt & 1;
    u16* ldsA = lds + bsel*32768;
    u16* ldsB = ldsA + 16384;
    u16* nA = lds + (bsel^1)*32768;
    u16* nB = nA + 16384;
    long k1 = (long)(jt+1) << 6;
    bool pref = (jt+1 < NT);
    if (pref){
      STAGE_A(0, k1, nA); STAGE_A(1, k1, nA);
      STAGE_B(0, k1, nB); STAGE_B(1, k1, nB);
      asm volatile("s_waitcnt vmcnt(4)" ::: "memory");
    } else {
      asm volatile("s_waitcnt vmcnt(0)" ::: "memory");
    }
    __builtin_amdgcn_s_barrier();
    __builtin_amdgcn_s_setprio(1);
    KHALF(0);
    __builtin_amdgcn_s_setprio(0);
    __builtin_amdgcn_sched_barrier(0);
    if (pref){
      STAGE_A(2, k1, nA); STAGE_A(3, k1, nA);
      STAGE_B(2, k1, nB); STAGE_B(3, k1, nB);
    }
    __builtin_amdgcn_sched_barrier(0);
    __builtin_amdgcn_s_setprio(1);
    KHALF(1);
    __builtin_amdgcn_s_setprio(0);
    __builtin_amdgcn_sched_barrier(0);
    __builtin_amdgcn_s_barrier();
  }

  if constexpr (EPI == 3){
    u16* act = (u16*)Cp;
    const float sc = 0.015625f;  // 1/sqrt(4096)
    #pragma unroll
    for (int a=0;a<8;a++){
      long rowb = (long)mtile*256 + wm*128 + a*16 + kg*4;
      #pragma unroll
      for (int r=0;r<4;r++){
        #pragma unroll
        for (int b=0;b<4;b++){
          float v = acc[a][b][r];
          float pv = __shfl_xor(v, 1);
          if (!(fr & 1)){
            int colg = ntile*256 + wn*64 + b*16 + fr;
            float g = pv;
            float sl = g / (1.0f + __expf(-g));
            act[(rowb+r)*ldc + (colg>>1)] = f2bf(v * sl * sc);
          }
        }
      }
    }
  } else { // EPI 4: f32 store + per-row LSE partials
    float* C = (float*)Cp;
    #pragma unroll
    for (int a=0;a<8;a++){
      long rowb = (long)mtile*256 + wm*128 + a*16 + kg*4;
      #pragma unroll
      for (int r=0;r<4;r++){
        #pragma unroll
        for (int b=0;b<4;b++){
          int colg = ntile*256 + wn*64 + b*16 + fr;
          C[(rowb+r)*ldc + colg] = acc[a][b][r];
        }
      }
    }
    float* pm = (float*)lds;          // [4][256]
    float* ps = pm + 1024;            // [4][256]
    #pragma unroll
    for (int a=0;a<8;a++)
      #pragma unroll
      for (int r=0;r<4;r++){
        float M = fmaxf(fmaxf(acc[a][0][r],acc[a][1][r]), fmaxf(acc[a][2][r],acc[a][3][r]));
        #pragma unroll
        for (int o=1;o<16;o<<=1) M = fmaxf(M, __shfl_xor(M, o));
        float S = __expf(acc[a][0][r]-M) + __expf(acc[a][1][r]-M)
                + __expf(acc[a][2][r]-M) + __expf(acc[a][3][r]-M);
        #pragma unroll
        for (int o=1;o<16;o<<=1) S += __shfl_xor(S, o);
        if (fr == 0){
          int rl = wm*128 + a*16 + kg*4 + r;
          pm[wn*256 + rl] = M; ps[wn*256 + rl] = S;
        }
      }
    __syncthreads();
    if (tid < 256){
      float m0 = pm[tid], m1 = pm[256+tid], m2 = pm[512+tid], m3 = pm[768+tid];
      float M = fmaxf(fmaxf(m0,m1), fmaxf(m2,m3));
      float S = ps[tid]*__expf(m0-M) + ps[256+tid]*__expf(m1-M)
              + ps[512+tid]*__expf(m2-M) + ps[768+tid]*__expf(m3-M);
      partials[((long)mtile*256 + tid)*128 + ntile] = make_float2(M, S);
    }
  }
#undef STAGE_A
#undef STAGE_B
#undef KHALF
}

// ---------------- transpose V -> vT[z][d][t'] (unit-swizzled within 128-tiles) ----------------
__global__ void k_transpose_v(const u16* __restrict__ qkv, u16* __restrict__ vT){
  int ttile = blockIdx.x; int z = blockIdx.y;
  long b = z >> 4; int hh = z & 15;
  const u16* v = qkv + b*TT*3072 + 2048 + hh*64;
  u16* outp = vT + (long)z*64*TT;
  __shared__ u16 ls[64][65];
  int u = threadIdx.x, rr = u & 63, cc = u >> 6;
  const u16* sp = v + (long)(ttile*64 + rr)*3072 + cc*16;
  us4 a0 = ((const us4*)sp)[0];
  us4 a1 = ((const us4*)sp)[1];
  us4 a2 = ((const us4*)sp)[2];
  us4 a3 = ((const us4*)sp)[3];
  #pragma unroll
  for (int j=0;j<4;j++){ ls[rr][cc*16+j] = a0[j]; ls[rr][cc*16+4+j] = a1[j];
                         ls[rr][cc*16+8+j] = a2[j]; ls[rr][cc*16+12+j] = a3[j]; }
  __syncthreads();
  int d = u & 63;
  #pragma unroll
  for (int g=0; g<4; ++g){
    int tl = cc*16 + g*4;
    int t  = ttile*64 + tl;
    int ut = (t >> 3) & 15;
    int tp = (t & ~127) + (((ut ^ (d & 15)) << 3) | (t & 7));
    us4 o = { ls[tl+0][d], ls[tl+1][d], ls[tl+2][d], ls[tl+3][d] };
    *((us4*)(outp + (long)d*TT + tp)) = o;
  }
}

// ---------------- fused flash attention (QBLK=32, 4 blocks/CU, lsP aliases lsK) ----------------
__global__ __launch_bounds__(128) void k_flash(
    const u16* __restrict__ qkv, const u16* __restrict__ vT, u16* __restrict__ attnb)
{
  __shared__ u16 lsQ[32*64];     // 4KB
  __shared__ u16 lsK[128*64];    // 16KB; first 8KB reused as P [32][128]
  __shared__ u16 lsV[64*128];    // 16KB
  u16* lsP = lsK;
  int id = blockIdx.x;
  int wq = id >> 5, z = id & 31;
  int qt = (wq < 16) ? wq : 47 - wq;
  long bT = (long)(z >> 4) * TT;
  int h64 = (z & 15) * 64;
  int t = threadIdx.x, wv = t >> 6, ln = t & 63;
  int fr = ln & 15, kg = ln >> 4;
  const u16* vbase = vT + (long)z*64*TT;

  #pragma unroll
  for (int p=0; p<2; ++p){
    int r = p*16 + wv*8 + (ln>>3);
    const u16* g = qkv + (bT + qt*32 + r)*3072 + h64 + (((ln&7) ^ (ln>>3))*8);
    gld_lds16(g, lsQ + (p*16 + wv*8)*64);
  }

  f32x4 S[8], O[4];
  float Mst[4], Lst[4];
  #pragma unroll
  for (int n=0;n<4;n++) O[n] = (f32x4){0.f,0.f,0.f,0.f};
  #pragma unroll
  for (int r=0;r<4;r++){ Mst[r] = -3.0e38f; Lst[r] = 0.f; }

  int nk = (qt >> 2) + 1;
  for (int kt = 0; kt < nk; ++kt){
    #pragma unroll
    for (int p=0; p<8; ++p){
      int r = p*16 + wv*8 + (ln>>3);
      const u16* g = qkv + (bT + kt*128 + r)*3072 + 1024 + h64 + (((ln&7) ^ (ln>>3))*8);
      gld_lds16(g, lsK + (p*16 + wv*8)*64);
    }
    #pragma unroll
    for (int p=0; p<8; ++p){
      int d = p*8 + wv*4 + (ln>>4);
      const u16* g = vbase + (long)d*TT + kt*128 + (ln&15)*8;
      gld_lds16(g, lsV + (p*8 + wv*4)*128);
    }
    __syncthreads();

    #pragma unroll
    for (int n=0;n<8;n++) S[n] = (f32x4){0.f,0.f,0.f,0.f};
    #pragma unroll
    for (int ks=0; ks<2; ++ks){
      int un = ((ks*4 + kg) ^ (fr & 7)) * 8;
      short8 a0 = *(const short8*)(lsQ + (wv*16 + fr)*64 + un);
      #pragma unroll
      for (int n=0;n<8;n++){
        short8 bb = *(const short8*)(lsK + (n*16 + fr)*64 + un);
        S[n] = __builtin_amdgcn_mfma_f32_16x16x32_bf16(a0, bb, S[n], 0,0,0);
      }
    }
    __syncthreads();   // all QK reads of lsK complete before P overwrites it

    #pragma unroll
    for (int r=0;r<4;r++){
      int rloc = wv*16 + kg*4 + r;
      int row_g = qt*32 + rloc;
      float x[8]; float mx = -3.0e38f;
      #pragma unroll
      for (int n=0;n<8;n++){
        int col_g = kt*128 + n*16 + fr;
        x[n] = (col_g <= row_g) ? S[n][r]*0.125f : -3.0e38f;
        mx = fmaxf(mx, x[n]);
      }
      #pragma unroll
      for (int o=1;o<16;o<<=1) mx = fmaxf(mx, __shfl_xor(mx, o));
      float Mnew = fmaxf(Mst[r], mx);
      float corr = __expf(Mst[r] - Mnew);
      Mst[r] = Mnew;
      float s = 0.f;
      #pragma unroll
      for (int n=0;n<8;n++){
        float p = __expf(x[n] - Mnew);
        s += p;
        int col = n*16 + fr;
        int col2 = ((((col>>3) ^ (rloc & 15)) << 3) | (col & 7));
        lsP[rloc*128 + col2] = f2bf(p);
      }
      #pragma unroll
      for (int o=1;o<16;o<<=1) s += __shfl_xor(s, o);
      Lst[r] = Lst[r]*corr + s;
      #pragma unroll
      for (int n=0;n<4;n++) O[n][r] *= corr;
    }

    #pragma unroll
    for (int ks=0; ks<4; ++ks){
      int up = ((ks*4 + kg) ^ fr) * 8;
      short8 p0 = *(const short8*)(lsP + (wv*16 + fr)*128 + up);
      #pragma unroll
      for (int n=0;n<4;n++){
        short8 vb = *(const short8*)(lsV + (n*16 + fr)*128 + up);
        O[n] = __builtin_amdgcn_mfma_f32_16x16x32_bf16(p0, vb, O[n], 0,0,0);
      }
    }
    __syncthreads();
  }

  #pragma unroll
  for (int r=0;r<4;r++){
    float inv = 1.0f / Lst[r];
    long row = bT + qt*32 + wv*16 + kg*4 + r;
    #pragma unroll
    for (int n=0;n<4;n++)
      attnb[row*1024 + h64 + n*16 + fr] = f2bf(O[n][r]*inv);
  }
}

// ---------------- NLL from partials ----------------
__global__ void k_nll2(const float2* __restrict__ part, const float* __restrict__ logits,
                       const int* __restrict__ labels, float* __restrict__ nll){
  int row = blockIdx.x; int ln = threadIdx.x;
  const float2* pr = part + (long)row*128;
  float m = -3.0e38f, s = 0.f;
  for (int j = ln; j < 125; j += 64){
    float2 p = pr[j];
    float M = fmaxf(m, p.x);
    s = s*__expf(m - M) + p.y*__expf(p.x - M);
    m = M;
  }
  #pragma unroll
  for (int o=32;o;o>>=1){
    float om = __shfl_xor(m, o), os = __shfl_xor(s, o);
    float M = fmaxf(m, om);
    s = s*__expf(m - M) + os*__expf(om - M);
    m = M;
  }
  if (ln == 0){
    int lab = labels[row];
    float lse = m + __logf(s);
    nll[row] = (lab != -1) ? (lse - logits[(long)row*VOCAB + lab]) : 0.f;
  }
}

__global__ void k_loss(const float* __restrict__ nll, const int* __restrict__ labels,
                       float* __restrict__ out){
  int tid = threadIdx.x;
  int wv = tid >> 6;
  float s = 0.f; float c = 0.f;
  for (int i = tid; i < MROWS; i += 256){
    s += nll[i];
    c += (labels[i] != -1) ? 1.f : 0.f;
  }
  #pragma unroll
  for (int o=32;o;o>>=1){ s += __shfl_xor(s, o); c += __shfl_xor(c, o); }
  __shared__ float rsm[4], rc[4];
  if ((tid & 63) == 0){ rsm[wv] = s; rc[wv] = c; }
  __syncthreads();
  if (tid == 0){
    s = rsm[0]+rsm[1]+rsm[2]+rsm[3];
    c = rc[0]+rc[1]+rc[2]+rc[3];
    out[(long)MROWS*VOCAB] = s / fmaxf(c, 1.f);
  }
}

extern "C" void kernel_launch(void* const* d_in, const int* in_sizes, int n_in,
                              void* d_out, int out_size, void* d_ws, size_t ws_size,
                              hipStream_t stream)
{
  (void)in_sizes; (void)n_in; (void)out_size; (void)ws_size;
  const int*   ids    = (const int*)d_in[0];
  const int*   labels = (const int*)d_in[1];
  const float* Wemb   = (const float*)d_in[2];
  const float* Wq     = (const float*)d_in[3];
  const float* Wk     = (const float*)d_in[4];
  const float* Wv     = (const float*)d_in[5];
  const float* Wo     = (const float*)d_in[6];
  const float* Wfc    = (const float*)d_in[7];
  const float* Wg     = (const float*)d_in[8];
  const float* Wp     = (const float*)d_in[9];
  float* logits = (float*)d_out;

  char* ws = (char*)d_ws;
  size_t off = 0;
  auto alloc = [&](size_t bytes){ void* p = ws + off; off += (bytes + 255) & ~(size_t)255; return p; };
  u16*    wembBf = (u16*)alloc((size_t)VOCAB*DIM*2);
  float*  h      = (float*)alloc((size_t)MROWS*DIM*4);
  u16*    hb     = (u16*)alloc((size_t)MROWS*DIM*2);
  u16*    qkvT   = (u16*)alloc((size_t)3*DIM*DIM*2);
  u16*    woT    = (u16*)alloc((size_t)DIM*DIM*2);
  u16*    fgT    = (u16*)alloc((size_t)2*HID*DIM*2);
  u16*    projT  = (u16*)alloc((size_t)DIM*HID*2);
  u16*    qkv    = (u16*)alloc((size_t)MROWS*3*DIM*2);
  u16*    vT     = (u16*)alloc((size_t)BB*NH*64*TT*2);
  u16*    attnb  = (u16*)alloc((size_t)MROWS*DIM*2);
  u16*    act    = (u16*)alloc((size_t)MROWS*HID*2);
  float*  pK     = (float*)alloc((size_t)4*MROWS*DIM*4);
  float2* parts  = (float2*)alloc((size_t)MROWS*128*8);
  float*  nllb   = (float*)alloc((size_t)MROWS*4);

  dim3 blk(256,1,1);
  dim3 blk512(512,1,1);
  const float aL = 0.35355339059327373f;   // 1/sqrt(L)

  k_cvt<<<dim3(16000,1,1),blk,0,stream>>>(Wemb, wembBf, (long)VOCAB*DIM);
  k_embed<<<dim3(MROWS,1,1),blk,0,stream>>>(ids, Wemb, h, hb);

  for (int l = 0; l < L_LAYERS; ++l){
    k_cvt_layer<<<dim3(4096,1,1),blk,0,stream>>>(
        Wq + (size_t)l*DIM*DIM, Wk + (size_t)l*DIM*DIM, Wv + (size_t)l*DIM*DIM, Wo + (size_t)l*DIM*DIM,
        Wfc + (size_t)l*DIM*HID, Wg + (size_t)l*DIM*HID, Wp + (size_t)l*HID*DIM,
        qkvT, woT, fgT, projT);
    // QKV: [2048,1024] x [3072,1024]^T -> qkv bf16
    k_gemm<0><<<dim3(384,1,1),blk,0,stream>>>(hb,1024, qkvT,1024, qkv,3072,
        1024,16,1.f,1, nullptr);
    k_transpose_v<<<dim3(16,32,1),blk,0,stream>>>(qkv, vT);
    // fused flash attention (QBLK=32, 1024 blocks)
    k_flash<<<dim3(1024,1,1),dim3(128,1,1),0,stream>>>(qkv, vT, attnb);
    // Wo split-K x2 -> partials, reduce + residual
    k_gemm<5><<<dim3(256,1,1),blk,0,stream>>>(attnb,1024, woT,1024, pK,1024,
        512,16,1.f,2, nullptr);
    k_redKn<2><<<dim3(2048,1,1),blk,0,stream>>>(pK, h, hb);
    // fc|gate interleaved + fused SwiGLU -> act  (256^2 dbuf, XCD-resident A)
    k_gemm256<3><<<dim3(256,1,1),blk512,0,stream>>>(hb,1024, fgT,1024, act,4096,
        1024,8, nullptr);
    // proj split-K x4 -> partials, reduce + residual
    k_gemm<5><<<dim3(512,1,1),blk,0,stream>>>(act,4096, projT,4096, pK,1024,
        1024,16,1.f,4, nullptr);
    k_redKn<4><<<dim3(2048,1,1),blk,0,stream>>>(pK, h, hb);
  }
  // lm head (256^2 dbuf, XCD-resident A) + NLL partials
  k_gemm256<4><<<dim3(1000,1,1),blk512,0,stream>>>(hb,1024, wembBf,1024, logits,32000,
      1024,8, parts);
  k_nll2<<<dim3(MROWS,1,1),dim3(64,1,1),0,stream>>>(parts, logits, labels, nllb);
  k_loss<<<dim3(1,1,1),blk,0,stream>>>(nllb, labels, logits);
}

// Round 15
// 1693.352 us; speedup vs baseline: 1.0118x; 1.0118x over previous
//
#include <hip/hip_runtime.h>
#include <hip/hip_bf16.h>
#include <math.h>

#define L_LAYERS 8
#define DIM 1024
#define NH 16
#define HD 64
#define HID 4096
#define VOCAB 32000
#define BB 2
#define TT 1024
#define MROWS (BB*TT)

typedef unsigned short u16;
typedef short short8 __attribute__((ext_vector_type(8)));
typedef float f32x4 __attribute__((ext_vector_type(4)));
typedef unsigned short us4 __attribute__((ext_vector_type(4)));
typedef unsigned short us8 __attribute__((ext_vector_type(8)));

__device__ __forceinline__ float bf2f(u16 x){
  union { unsigned int u; float f; } v; v.u = ((unsigned int)x) << 16; return v.f;
}
__device__ __forceinline__ u16 f2bf(float f){
  union { float f; unsigned int u; } v; v.f = f;
  unsigned int r = (v.u + 0x7fffu + ((v.u >> 16) & 1u)) >> 16; return (u16)r;
}

#define AS1 __attribute__((address_space(1)))
#define AS3 __attribute__((address_space(3)))
__device__ __forceinline__ void gld_lds16(const void* g, void* l){
  __builtin_amdgcn_global_load_lds((const AS1 void*)g, (AS3 void*)l, 16, 0, 0);
}

// ---------------- embedding ----------------
__global__ void k_embed(const int* __restrict__ ids, const float* __restrict__ Wemb,
                        float* __restrict__ h, u16* __restrict__ hb){
  int bt = blockIdx.x; long id = ids[bt];
  const float4* src = (const float4*)(Wemb + id*(long)DIM);
  float4 v = src[threadIdx.x];
  ((float4*)(h + (long)bt*DIM))[threadIdx.x] = v;
  us4 o = { f2bf(v.x), f2bf(v.y), f2bf(v.z), f2bf(v.w) };
  ((us4*)(hb + (long)bt*DIM))[threadIdx.x] = o;
}

// ---------------- f32 -> bf16 elementwise (Wemb) ----------------
__global__ void k_cvt(const float* __restrict__ src, u16* __restrict__ dst, long n){
  long i = ((long)blockIdx.x*256 + threadIdx.x)*8;
  if (i >= n) return;
  float4 a = ((const float4*)(src+i))[0];
  float4 b = ((const float4*)(src+i))[1];
  us4 o0 = { f2bf(a.x), f2bf(a.y), f2bf(a.z), f2bf(a.w) };
  us4 o1 = { f2bf(b.x), f2bf(b.y), f2bf(b.z), f2bf(b.w) };
  ((us4*)(dst+i))[0] = o0; ((us4*)(dst+i))[1] = o1;
}

// ---------------- per-layer weight convert + transpose (coalesced both sides) ----------------
__global__ void k_cvt_layer(const float* __restrict__ Wq, const float* __restrict__ Wk,
    const float* __restrict__ Wv, const float* __restrict__ Wo,
    const float* __restrict__ Wfc, const float* __restrict__ Wg, const float* __restrict__ Wp,
    u16* __restrict__ qkvT, u16* __restrict__ woT, u16* __restrict__ fgT, u16* __restrict__ projT)
{
  int tile = blockIdx.x;
  const float* src; u16* dst; int R, C, tr, tc;
  long rowmul = 1, rowoff = 0;
  if (tile < 1024){
    int m = tile >> 8, t2 = tile & 255;
    tr = t2 >> 4; tc = t2 & 15; R = 1024; C = 1024;
    src = (m==0)?Wq:(m==1)?Wk:(m==2)?Wv:Wo;
    dst = (m<3)? qkvT + (long)m*1024*1024 : woT;
  } else if (tile < 3072){
    int m = (tile - 1024) >> 10, t2 = (tile - 1024) & 1023;
    tr = t2 >> 6; tc = t2 & 63; R = 1024; C = 4096;
    src = m ? Wg : Wfc; dst = fgT; rowmul = 2; rowoff = m;
  } else {
    int t2 = tile - 3072;
    tr = t2 >> 4; tc = t2 & 15; R = 4096; C = 1024;
    src = Wp; dst = projT;
  }
  __shared__ float ls[64][65];
  int u = threadIdx.x;
  int rr16 = u >> 4;
  int cu   = u & 15;
  #pragma unroll
  for (int p = 0; p < 4; ++p){
    int r = p*16 + rr16;
    float4 v = *(const float4*)(src + (long)(tr*64 + r)*C + tc*64 + cu*4);
    ls[r][cu*4+0]=v.x; ls[r][cu*4+1]=v.y; ls[r][cu*4+2]=v.z; ls[r][cu*4+3]=v.w;
  }
  __syncthreads();
  int d  = u >> 2;
  int c4 = u & 3;
  long drow = (long)tc*64 + d;
  u16* dp = dst + (drow*rowmul + rowoff)*R + tr*64;
  #pragma unroll
  for (int g2 = 0; g2 < 2; ++g2){
    int e0 = (c4 + g2*4) * 8;
    us8 o;
    #pragma unroll
    for (int j=0;j<8;j++) o[j] = f2bf(ls[e0+j][d]);
    *((us8*)(dp + e0)) = o;
  }
}

// ============ 128-tile bf16 GEMM (qkv / wo-splitK / proj-splitK) ============
template<int EPI>
__global__ __launch_bounds__(256, 2) void k_gemm(
    const u16* __restrict__ A, long lda,
    const u16* __restrict__ Bt, long ldb,
    void* __restrict__ Cp, long ldc,
    int K, int nMt, float alpha, int ksplit,
    u16* __restrict__ hbout)
{
  __shared__ u16 lsA[128*32];
  __shared__ u16 lsB[128*32];
  int nflat = gridDim.x; int w = blockIdx.x;
  if ((nflat & 7) == 0){ int q = nflat >> 3; w = (w & 7)*q + (w >> 3); }
  int perk = nflat / ksplit;
  int kc = w / perk; int w2 = w - kc*perk;
  int mtile = w2 % nMt, ntile = w2 / nMt;
  const u16* Ab = A + (long)mtile*128*lda + (long)kc*K;
  const u16* Bb = Bt + (long)ntile*128*ldb + (long)kc*K;
  int t = threadIdx.x;
  int wv = t >> 6, ln = t & 63;
  int srow = t >> 2;
  int scol = (t & 3) * 8;
  int fr = ln & 15, kg = ln >> 4;
  int wr = wv >> 1, wc = wv & 1;
  const f32x4 zero = {0.f,0.f,0.f,0.f};
  f32x4 acc[4][4];
  #pragma unroll
  for (int m=0;m<4;m++)
    #pragma unroll
    for (int n=0;n<4;n++) acc[m][n] = zero;
  const u16* ga0 = Ab + (long)srow*lda + scol;
  const u16* ga1 = Ab + (long)(srow+64)*lda + scol;
  const u16* gb0 = Bb + (long)srow*ldb + scol;
  const u16* gb1 = Bb + (long)(srow+64)*ldb + scol;
  u16* la0 = lsA + wv*512;
  u16* la1 = lsA + 2048 + wv*512;
  u16* lb0 = lsB + wv*512;
  u16* lb1 = lsB + 2048 + wv*512;
  for (int k0 = 0; k0 < K; k0 += 32){
    gld_lds16(ga0 + k0, la0);
    gld_lds16(ga1 + k0, la1);
    gld_lds16(gb0 + k0, lb0);
    gld_lds16(gb1 + k0, lb1);
    __syncthreads();
    short8 af[4], bfr[4];
    #pragma unroll
    for (int m=0;m<4;m++) af[m]  = *(const short8*)(lsA + (wr*64 + m*16 + fr)*32 + kg*8);
    #pragma unroll
    for (int n=0;n<4;n++) bfr[n] = *(const short8*)(lsB + (wc*64 + n*16 + fr)*32 + kg*8);
    #pragma unroll
    for (int m=0;m<4;m++)
      #pragma unroll
      for (int n=0;n<4;n++)
        acc[m][n] = __builtin_amdgcn_mfma_f32_16x16x32_bf16(af[m], bfr[n], acc[m][n], 0, 0, 0);
    __syncthreads();
  }
  long row0 = (long)mtile*128 + wr*64 + kg*4;
  int col0 = ntile*128 + wc*64 + fr;
  if constexpr (EPI == 0){
    u16* C = (u16*)Cp;
    #pragma unroll
    for (int m=0;m<4;m++)
      #pragma unroll
      for (int r=0;r<4;r++){
        long row = row0 + m*16 + r;
        #pragma unroll
        for (int n=0;n<4;n++) C[row*ldc + col0 + n*16] = f2bf(acc[m][n][r]);
      }
  } else if constexpr (EPI == 2){
    float* C = (float*)Cp;
    #pragma unroll
    for (int m=0;m<4;m++)
      #pragma unroll
      for (int r=0;r<4;r++){
        long row = row0 + m*16 + r;
        #pragma unroll
        for (int n=0;n<4;n++){
          long idx = row*ldc + col0 + n*16;
          float v = C[idx] + acc[m][n][r]*alpha;
          C[idx] = v;
          hbout[idx] = f2bf(v);
        }
      }
  } else { // EPI 5
    float* C = (float*)Cp + (long)kc*MROWS*ldc;
    #pragma unroll
    for (int m=0;m<4;m++)
      #pragma unroll
      for (int r=0;r<4;r++){
        long row = row0 + m*16 + r;
        #pragma unroll
        for (int n=0;n<4;n++) C[row*ldc + col0 + n*16] = acc[m][n][r];
      }
  }
}

// ---------------- split-K reduce (NS partials) + residual ----------------
template<int NS>
__global__ void k_redKn(const float* __restrict__ pK, float* __restrict__ h, u16* __restrict__ hb){
  long idx = ((long)blockIdx.x*256 + threadIdx.x)*4;
  const float aL = 0.35355339059327373f;
  float4 s = *(const float4*)(pK + idx);
  #pragma unroll
  for (int j=1;j<NS;j++){
    float4 sj = *(const float4*)(pK + idx + (long)j*MROWS*1024);
    s.x += sj.x; s.y += sj.y; s.z += sj.z; s.w += sj.w;
  }
  float4 hv = *(const float4*)(h + idx);
  float4 v;
  v.x = hv.x + s.x*aL;
  v.y = hv.y + s.y*aL;
  v.z = hv.z + s.z*aL;
  v.w = hv.w + s.w*aL;
  *(float4*)(h + idx) = v;
  us4 o = { f2bf(v.x), f2bf(v.y), f2bf(v.z), f2bf(v.w) };
  *(us4*)(hb + idx) = o;
}

// ============ 256x256 8-wave BK=64 GEMM, 2-phase + register-reuse (fg / lm_head) ============
// NFAST=1: ntile-fastest within XCD chunk (A-panel L2-resident per XCD) — lm_head.
// NFAST=0: mtile-fastest (original) — fg.
#define MFMA_(va,vb,vc) __builtin_amdgcn_mfma_f32_16x16x32_bf16(va,vb,vc,0,0,0)
#define RD2(base, row, ku) (*(const short8*)((base) + (row)*64 + ((((ku) ^ ((row)&7)))<<3)))

template<int EPI, int NFAST>
__global__ __launch_bounds__(512, 1) void k_gemm256(
    const u16* __restrict__ A, long lda,
    const u16* __restrict__ Bt, long ldb,
    void* __restrict__ Cp, long ldc,
    int K, int nMt,
    float2* __restrict__ partials)
{
  __shared__ u16 lds[65536];   // [A0 32KB][B0 32KB][A1 32KB][B1 32KB]
  int nwg = gridDim.x; int w = blockIdx.x;
  { int q = nwg >> 3, r8 = nwg & 7; int xcd = w & 7, lw = w >> 3;
    w = (xcd < r8 ? xcd*(q+1) : r8*(q+1) + (xcd-r8)*q) + lw; }
  int mtile, ntile;
  if constexpr (NFAST){
    int nNt = nwg / nMt;
    ntile = w % nNt; mtile = w / nNt;
  } else {
    mtile = w % nMt; ntile = w / nMt;
  }
  const u16* Abase = A + (long)mtile*256*lda;
  const u16* Bbase = Bt + (long)ntile*256*ldb;
  int tid = threadIdx.x;
  int wid = tid >> 6, ln = tid & 63;
  int wm = wid >> 2, wn = wid & 3;
  int fr = ln & 15, kg = ln >> 4;

  f32x4 acc[8][4];
  #pragma unroll
  for (int a=0;a<8;a++)
    #pragma unroll
    for (int b=0;b<4;b++) acc[a][b] = (f32x4){0.f,0.f,0.f,0.f};

#define STAGE_A(i, kofs, dstbase) do{ \
    int u_ = (i)*512 + tid; int r_ = u_>>3; int cu_ = u_&7; \
    gld_lds16(Abase + (long)r_*lda + (kofs) + ((cu_^(r_&7))<<3), \
              (dstbase) + (((i)*512 + wid*64)<<3)); }while(0)
#define STAGE_B(i, kofs, dstbase) do{ \
    int u_ = (i)*512 + tid; int r_ = u_>>3; int cu_ = u_&7; \
    gld_lds16(Bbase + (long)r_*ldb + (kofs) + ((cu_^(r_&7))<<3), \
              (dstbase) + (((i)*512 + wid*64)<<3)); }while(0)

#define KHALF(ks) do{ \
    short8 a0 = RD2(ldsA, wm*128 +   0 + fr, (ks)*4+kg); \
    short8 a1 = RD2(ldsA, wm*128 +  16 + fr, (ks)*4+kg); \
    short8 a2 = RD2(ldsA, wm*128 +  32 + fr, (ks)*4+kg); \
    short8 a3 = RD2(ldsA, wm*128 +  48 + fr, (ks)*4+kg); \
    short8 a4 = RD2(ldsA, wm*128 +  64 + fr, (ks)*4+kg); \
    short8 a5 = RD2(ldsA, wm*128 +  80 + fr, (ks)*4+kg); \
    short8 a6 = RD2(ldsA, wm*128 +  96 + fr, (ks)*4+kg); \
    short8 a7 = RD2(ldsA, wm*128 + 112 + fr, (ks)*4+kg); \
    short8 b0 = RD2(ldsB, wn*64 +  0 + fr, (ks)*4+kg); \
    short8 b1 = RD2(ldsB, wn*64 + 16 + fr, (ks)*4+kg); \
    short8 b2 = RD2(ldsB, wn*64 + 32 + fr, (ks)*4+kg); \
    short8 b3 = RD2(ldsB, wn*64 + 48 + fr, (ks)*4+kg); \
    acc[0][0]=MFMA_(a0,b0,acc[0][0]); acc[1][0]=MFMA_(a1,b0,acc[1][0]); \
    acc[0][1]=MFMA_(a0,b1,acc[0][1]); acc[1][1]=MFMA_(a1,b1,acc[1][1]); \
    acc[2][0]=MFMA_(a2,b0,acc[2][0]); acc[3][0]=MFMA_(a3,b0,acc[3][0]); \
    acc[2][1]=MFMA_(a2,b1,acc[2][1]); acc[3][1]=MFMA_(a3,b1,acc[3][1]); \
    acc[0][2]=MFMA_(a0,b2,acc[0][2]); acc[1][2]=MFMA_(a1,b2,acc[1][2]); \
    acc[0][3]=MFMA_(a0,b3,acc[0][3]); acc[1][3]=MFMA_(a1,b3,acc[1][3]); \
    acc[2][2]=MFMA_(a2,b2,acc[2][2]); acc[3][2]=MFMA_(a3,b2,acc[3][2]); \
    acc[2][3]=MFMA_(a2,b3,acc[2][3]); acc[3][3]=MFMA_(a3,b3,acc[3][3]); \
    acc[4][0]=MFMA_(a4,b0,acc[4][0]); acc[5][0]=MFMA_(a5,b0,acc[5][0]); \
    acc[4][1]=MFMA_(a4,b1,acc[4][1]); acc[5][1]=MFMA_(a5,b1,acc[5][1]); \
    acc[6][0]=MFMA_(a6,b0,acc[6][0]); acc[7][0]=MFMA_(a7,b0,acc[7][0]); \
    acc[6][1]=MFMA_(a6,b1,acc[6][1]); acc[7][1]=MFMA_(a7,b1,acc[7][1]); \
    acc[4][2]=MFMA_(a4,b2,acc[4][2]); acc[5][2]=MFMA_(a5,b2,acc[5][2]); \
    acc[4][3]=MFMA_(a4,b3,acc[4][3]); acc[5][3]=MFMA_(a5,b3,acc[5][3]); \
    acc[6][2]=MFMA_(a6,b2,acc[6][2]); acc[7][2]=MFMA_(a7,b2,acc[7][2]); \
    acc[6][3]=MFMA_(a6,b3,acc[6][3]); acc[7][3]=MFMA_(a7,b3,acc[7][3]); \
  }while(0)

  // prologue: stage tile 0 into buffer 0
  {
    u16* dA = lds; u16* dB = lds + 16384;
    STAGE_A(0, 0, dA); STAGE_A(1, 0, dA); STAGE_A(2, 0, dA); STAGE_A(3, 0, dA);
    STAGE_B(0, 0, dB); STAGE_B(1, 0, dB); STAGE_B(2, 0, dB); STAGE_B(3, 0, dB);
  }
  const int NT = K >> 6;
  #pragma unroll 2
  for (int jt = 0; jt < NT; ++jt){
    int bsel = jt & 1;
    u16* ldsA = lds + bsel*32768;
    u16* ldsB = ldsA + 16384;
    u16* nA = lds + (bsel^1)*32768;
    u16* nB = nA + 16384;
    long k1 = (long)(jt+1) << 6;
    bool pref = (jt+1 < NT);
    if (pref){
      STAGE_A(0, k1, nA); STAGE_A(1, k1, nA);
      STAGE_B(0, k1, nB); STAGE_B(1, k1, nB);
      asm volatile("s_waitcnt vmcnt(4)" ::: "memory");
    } else {
      asm volatile("s_waitcnt vmcnt(0)" ::: "memory");
    }
    __builtin_amdgcn_s_barrier();
    __builtin_amdgcn_s_setprio(1);
    KHALF(0);
    __builtin_amdgcn_s_setprio(0);
    __builtin_amdgcn_sched_barrier(0);
    if (pref){
      STAGE_A(2, k1, nA); STAGE_A(3, k1, nA);
      STAGE_B(2, k1, nB); STAGE_B(3, k1, nB);
    }
    __builtin_amdgcn_sched_barrier(0);
    __builtin_amdgcn_s_setprio(1);
    KHALF(1);
    __builtin_amdgcn_s_setprio(0);
    __builtin_amdgcn_sched_barrier(0);
    __builtin_amdgcn_s_barrier();
  }

  if constexpr (EPI == 3){
    u16* act = (u16*)Cp;
    const float sc = 0.015625f;  // 1/sqrt(4096)
    #pragma unroll
    for (int a=0;a<8;a++){
      long rowb = (long)mtile*256 + wm*128 + a*16 + kg*4;
      #pragma unroll
      for (int r=0;r<4;r++){
        #pragma unroll
        for (int b=0;b<4;b++){
          float v = acc[a][b][r];
          float pv = __shfl_xor(v, 1);
          if (!(fr & 1)){
            int colg = ntile*256 + wn*64 + b*16 + fr;
            float g = pv;
            float sl = g / (1.0f + __expf(-g));
            act[(rowb+r)*ldc + (colg>>1)] = f2bf(v * sl * sc);
          }
        }
      }
    }
  } else { // EPI 4: f32 store + per-row LSE partials
    float* C = (float*)Cp;
    #pragma unroll
    for (int a=0;a<8;a++){
      long rowb = (long)mtile*256 + wm*128 + a*16 + kg*4;
      #pragma unroll
      for (int r=0;r<4;r++){
        #pragma unroll
        for (int b=0;b<4;b++){
          int colg = ntile*256 + wn*64 + b*16 + fr;
          C[(rowb+r)*ldc + colg] = acc[a][b][r];
        }
      }
    }
    float* pm = (float*)lds;          // [4][256]
    float* ps = pm + 1024;            // [4][256]
    #pragma unroll
    for (int a=0;a<8;a++)
      #pragma unroll
      for (int r=0;r<4;r++){
        float M = fmaxf(fmaxf(acc[a][0][r],acc[a][1][r]), fmaxf(acc[a][2][r],acc[a][3][r]));
        #pragma unroll
        for (int o=1;o<16;o<<=1) M = fmaxf(M, __shfl_xor(M, o));
        float S = __expf(acc[a][0][r]-M) + __expf(acc[a][1][r]-M)
                + __expf(acc[a][2][r]-M) + __expf(acc[a][3][r]-M);
        #pragma unroll
        for (int o=1;o<16;o<<=1) S += __shfl_xor(S, o);
        if (fr == 0){
          int rl = wm*128 + a*16 + kg*4 + r;
          pm[wn*256 + rl] = M; ps[wn*256 + rl] = S;
        }
      }
    __syncthreads();
    if (tid < 256){
      float m0 = pm[tid], m1 = pm[256+tid], m2 = pm[512+tid], m3 = pm[768+tid];
      float M = fmaxf(fmaxf(m0,m1), fmaxf(m2,m3));
      float S = ps[tid]*__expf(m0-M) + ps[256+tid]*__expf(m1-M)
              + ps[512+tid]*__expf(m2-M) + ps[768+tid]*__expf(m3-M);
      partials[((long)mtile*256 + tid)*128 + ntile] = make_float2(M, S);
    }
  }
#undef STAGE_A
#undef STAGE_B
#undef KHALF
}

// ---------------- transpose V -> vT[z][d][t'] (unit-swizzled within 128-tiles) ----------------
__global__ void k_transpose_v(const u16* __restrict__ qkv, u16* __restrict__ vT){
  int ttile = blockIdx.x; int z = blockIdx.y;
  long b = z >> 4; int hh = z & 15;
  const u16* v = qkv + b*TT*3072 + 2048 + hh*64;
  u16* outp = vT + (long)z*64*TT;
  __shared__ u16 ls[64][65];
  int u = threadIdx.x, rr = u & 63, cc = u >> 6;
  const u16* sp = v + (long)(ttile*64 + rr)*3072 + cc*16;
  us4 a0 = ((const us4*)sp)[0];
  us4 a1 = ((const us4*)sp)[1];
  us4 a2 = ((const us4*)sp)[2];
  us4 a3 = ((const us4*)sp)[3];
  #pragma unroll
  for (int j=0;j<4;j++){ ls[rr][cc*16+j] = a0[j]; ls[rr][cc*16+4+j] = a1[j];
                         ls[rr][cc*16+8+j] = a2[j]; ls[rr][cc*16+12+j] = a3[j]; }
  __syncthreads();
  int d = u & 63;
  #pragma unroll
  for (int g=0; g<4; ++g){
    int tl = cc*16 + g*4;
    int t  = ttile*64 + tl;
    int ut = (t >> 3) & 15;
    int tp = (t & ~127) + (((ut ^ (d & 15)) << 3) | (t & 7));
    us4 o = { ls[tl+0][d], ls[tl+1][d], ls[tl+2][d], ls[tl+3][d] };
    *((us4*)(outp + (long)d*TT + tp)) = o;
  }
}

// ---------------- fused flash attention (QBLK=32, 4 blocks/CU, lsP aliases lsK) ----------------
__global__ __launch_bounds__(128) void k_flash(
    const u16* __restrict__ qkv, const u16* __restrict__ vT, u16* __restrict__ attnb)
{
  __shared__ u16 lsQ[32*64];     // 4KB
  __shared__ u16 lsK[128*64];    // 16KB; first 8KB reused as P [32][128]
  __shared__ u16 lsV[64*128];    // 16KB
  u16* lsP = lsK;
  int id = blockIdx.x;
  int wq = id >> 5, z = id & 31;
  int qt = (wq < 16) ? wq : 47 - wq;
  long bT = (long)(z >> 4) * TT;
  int h64 = (z & 15) * 64;
  int t = threadIdx.x, wv = t >> 6, ln = t & 63;
  int fr = ln & 15, kg = ln >> 4;
  const u16* vbase = vT + (long)z*64*TT;

  #pragma unroll
  for (int p=0; p<2; ++p){
    int r = p*16 + wv*8 + (ln>>3);
    const u16* g = qkv + (bT + qt*32 + r)*3072 + h64 + (((ln&7) ^ (ln>>3))*8);
    gld_lds16(g, lsQ + (p*16 + wv*8)*64);
  }

  f32x4 S[8], O[4];
  float Mst[4], Lst[4];
  #pragma unroll
  for (int n=0;n<4;n++) O[n] = (f32x4){0.f,0.f,0.f,0.f};
  #pragma unroll
  for (int r=0;r<4;r++){ Mst[r] = -3.0e38f; Lst[r] = 0.f; }

  int nk = (qt >> 2) + 1;
  for (int kt = 0; kt < nk; ++kt){
    #pragma unroll
    for (int p=0; p<8; ++p){
      int r = p*16 + wv*8 + (ln>>3);
      const u16* g = qkv + (bT + kt*128 + r)*3072 + 1024 + h64 + (((ln&7) ^ (ln>>3))*8);
      gld_lds16(g, lsK + (p*16 + wv*8)*64);
    }
    #pragma unroll
    for (int p=0; p<8; ++p){
      int d = p*8 + wv*4 + (ln>>4);
      const u16* g = vbase + (long)d*TT + kt*128 + (ln&15)*8;
      gld_lds16(g, lsV + (p*8 + wv*4)*128);
    }
    __syncthreads();

    #pragma unroll
    for (int n=0;n<8;n++) S[n] = (f32x4){0.f,0.f,0.f,0.f};
    #pragma unroll
    for (int ks=0; ks<2; ++ks){
      int un = ((ks*4 + kg) ^ (fr & 7)) * 8;
      short8 a0 = *(const short8*)(lsQ + (wv*16 + fr)*64 + un);
      #pragma unroll
      for (int n=0;n<8;n++){
        short8 bb = *(const short8*)(lsK + (n*16 + fr)*64 + un);
        S[n] = __builtin_amdgcn_mfma_f32_16x16x32_bf16(a0, bb, S[n], 0,0,0);
      }
    }
    __syncthreads();   // all QK reads of lsK complete before P overwrites it

    #pragma unroll
    for (int r=0;r<4;r++){
      int rloc = wv*16 + kg*4 + r;
      int row_g = qt*32 + rloc;
      float x[8]; float mx = -3.0e38f;
      #pragma unroll
      for (int n=0;n<8;n++){
        int col_g = kt*128 + n*16 + fr;
        x[n] = (col_g <= row_g) ? S[n][r]*0.125f : -3.0e38f;
        mx = fmaxf(mx, x[n]);
      }
      #pragma unroll
      for (int o=1;o<16;o<<=1) mx = fmaxf(mx, __shfl_xor(mx, o));
      float Mnew = fmaxf(Mst[r], mx);
      float corr = __expf(Mst[r] - Mnew);
      Mst[r] = Mnew;
      float s = 0.f;
      #pragma unroll
      for (int n=0;n<8;n++){
        float p = __expf(x[n] - Mnew);
        s += p;
        int col = n*16 + fr;
        int col2 = ((((col>>3) ^ (rloc & 15)) << 3) | (col & 7));
        lsP[rloc*128 + col2] = f2bf(p);
      }
      #pragma unroll
      for (int o=1;o<16;o<<=1) s += __shfl_xor(s, o);
      Lst[r] = Lst[r]*corr + s;
      #pragma unroll
      for (int n=0;n<4;n++) O[n][r] *= corr;
    }

    #pragma unroll
    for (int ks=0; ks<4; ++ks){
      int up = ((ks*4 + kg) ^ fr) * 8;
      short8 p0 = *(const short8*)(lsP + (wv*16 + fr)*128 + up);
      #pragma unroll
      for (int n=0;n<4;n++){
        short8 vb = *(const short8*)(lsV + (n*16 + fr)*128 + up);
        O[n] = __builtin_amdgcn_mfma_f32_16x16x32_bf16(p0, vb, O[n], 0,0,0);
      }
    }
    __syncthreads();
  }

  #pragma unroll
  for (int r=0;r<4;r++){
    float inv = 1.0f / Lst[r];
    long row = bT + qt*32 + wv*16 + kg*4 + r;
    #pragma unroll
    for (int n=0;n<4;n++)
      attnb[row*1024 + h64 + n*16 + fr] = f2bf(O[n][r]*inv);
  }
}

// ---------------- NLL from partials ----------------
__global__ void k_nll2(const float2* __restrict__ part, const float* __restrict__ logits,
                       const int* __restrict__ labels, float* __restrict__ nll){
  int row = blockIdx.x; int ln = threadIdx.x;
  const float2* pr = part + (long)row*128;
  float m = -3.0e38f, s = 0.f;
  for (int j = ln; j < 125; j += 64){
    float2 p = pr[j];
    float M = fmaxf(m, p.x);
    s = s*__expf(m - M) + p.y*__expf(p.x - M);
    m = M;
  }
  #pragma unroll
  for (int o=32;o;o>>=1){
    float om = __shfl_xor(m, o), os = __shfl_xor(s, o);
    float M = fmaxf(m, om);
    s = s*__expf(m - M) + os*__expf(om - M);
    m = M;
  }
  if (ln == 0){
    int lab = labels[row];
    float lse = m + __logf(s);
    nll[row] = (lab != -1) ? (lse - logits[(long)row*VOCAB + lab]) : 0.f;
  }
}

__global__ void k_loss(const float* __restrict__ nll, const int* __restrict__ labels,
                       float* __restrict__ out){
  int tid = threadIdx.x;
  int wv = tid >> 6;
  float s = 0.f; float c = 0.f;
  for (int i = tid; i < MROWS; i += 256){
    s += nll[i];
    c += (labels[i] != -1) ? 1.f : 0.f;
  }
  #pragma unroll
  for (int o=32;o;o>>=1){ s += __shfl_xor(s, o); c += __shfl_xor(c, o); }
  __shared__ float rsm[4], rc[4];
  if ((tid & 63) == 0){ rsm[wv] = s; rc[wv] = c; }
  __syncthreads();
  if (tid == 0){
    s = rsm[0]+rsm[1]+rsm[2]+rsm[3];
    c = rc[0]+rc[1]+rc[2]+rc[3];
    out[(long)MROWS*VOCAB] = s / fmaxf(c, 1.f);
  }
}

extern "C" void kernel_launch(void* const* d_in, const int* in_sizes, int n_in,
                              void* d_out, int out_size, void* d_ws, size_t ws_size,
                              hipStream_t stream)
{
  (void)in_sizes; (void)n_in; (void)out_size; (void)ws_size;
  const int*   ids    = (const int*)d_in[0];
  const int*   labels = (const int*)d_in[1];
  const float* Wemb   = (const float*)d_in[2];
  const float* Wq     = (const float*)d_in[3];
  const float* Wk     = (const float*)d_in[4];
  const float* Wv     = (const float*)d_in[5];
  const float* Wo     = (const float*)d_in[6];
  const float* Wfc    = (const float*)d_in[7];
  const float* Wg     = (const float*)d_in[8];
  const float* Wp     = (const float*)d_in[9];
  float* logits = (float*)d_out;

  char* ws = (char*)d_ws;
  size_t off = 0;
  auto alloc = [&](size_t bytes){ void* p = ws + off; off += (bytes + 255) & ~(size_t)255; return p; };
  u16*    wembBf = (u16*)alloc((size_t)VOCAB*DIM*2);
  float*  h      = (float*)alloc((size_t)MROWS*DIM*4);
  u16*    hb     = (u16*)alloc((size_t)MROWS*DIM*2);
  u16*    qkvT   = (u16*)alloc((size_t)3*DIM*DIM*2);
  u16*    woT    = (u16*)alloc((size_t)DIM*DIM*2);
  u16*    fgT    = (u16*)alloc((size_t)2*HID*DIM*2);
  u16*    projT  = (u16*)alloc((size_t)DIM*HID*2);
  u16*    qkv    = (u16*)alloc((size_t)MROWS*3*DIM*2);
  u16*    vT     = (u16*)alloc((size_t)BB*NH*64*TT*2);
  u16*    attnb  = (u16*)alloc((size_t)MROWS*DIM*2);
  u16*    act    = (u16*)alloc((size_t)MROWS*HID*2);
  float*  pK     = (float*)alloc((size_t)4*MROWS*DIM*4);
  float2* parts  = (float2*)alloc((size_t)MROWS*128*8);
  float*  nllb   = (float*)alloc((size_t)MROWS*4);

  dim3 blk(256,1,1);
  dim3 blk512(512,1,1);
  const float aL = 0.35355339059327373f;   // 1/sqrt(L)

  k_cvt<<<dim3(16000,1,1),blk,0,stream>>>(Wemb, wembBf, (long)VOCAB*DIM);
  k_embed<<<dim3(MROWS,1,1),blk,0,stream>>>(ids, Wemb, h, hb);

  for (int l = 0; l < L_LAYERS; ++l){
    k_cvt_layer<<<dim3(4096,1,1),blk,0,stream>>>(
        Wq + (size_t)l*DIM*DIM, Wk + (size_t)l*DIM*DIM, Wv + (size_t)l*DIM*DIM, Wo + (size_t)l*DIM*DIM,
        Wfc + (size_t)l*DIM*HID, Wg + (size_t)l*DIM*HID, Wp + (size_t)l*HID*DIM,
        qkvT, woT, fgT, projT);
    // QKV: [2048,1024] x [3072,1024]^T -> qkv bf16
    k_gemm<0><<<dim3(384,1,1),blk,0,stream>>>(hb,1024, qkvT,1024, qkv,3072,
        1024,16,1.f,1, nullptr);
    k_transpose_v<<<dim3(16,32,1),blk,0,stream>>>(qkv, vT);
    // fused flash attention (QBLK=32, 1024 blocks)
    k_flash<<<dim3(1024,1,1),dim3(128,1,1),0,stream>>>(qkv, vT, attnb);
    // Wo split-K x2 -> partials, reduce + residual
    k_gemm<5><<<dim3(256,1,1),blk,0,stream>>>(attnb,1024, woT,1024, pK,1024,
        512,16,1.f,2, nullptr);
    k_redKn<2><<<dim3(2048,1,1),blk,0,stream>>>(pK, h, hb);
    // fc|gate interleaved + fused SwiGLU -> act  (256^2 dbuf, m-fastest)
    k_gemm256<3,0><<<dim3(256,1,1),blk512,0,stream>>>(hb,1024, fgT,1024, act,4096,
        1024,8, nullptr);
    // proj split-K x4 -> partials, reduce + residual
    k_gemm<5><<<dim3(512,1,1),blk,0,stream>>>(act,4096, projT,4096, pK,1024,
        1024,16,1.f,4, nullptr);
    k_redKn<4><<<dim3(2048,1,1),blk,0,stream>>>(pK, h, hb);
  }
  // lm head (256^2 dbuf, XCD-resident A / n-fastest) + NLL partials
  k_gemm256<4,1><<<dim3(1000,1,1),blk512,0,stream>>>(hb,1024, wembBf,1024, logits,32000,
      1024,8, parts);
  k_nll2<<<dim3(MROWS,1,1),dim3(64,1,1),0,stream>>>(parts, logits, labels, nllb);
  k_loss<<<dim3(1,1,1),blk,0,stream>>>(nllb, labels, logits);
}

// Round 16
// 1646.326 us; speedup vs baseline: 1.0407x; 1.0286x over previous
//
#include <hip/hip_runtime.h>
#include <hip/hip_bf16.h>
#include <math.h>

#define L_LAYERS 8
#define DIM 1024
#define NH 16
#define HD 64
#define HID 4096
#define VOCAB 32000
#define BB 2
#define TT 1024
#define MROWS (BB*TT)

typedef unsigned short u16;
typedef short short8 __attribute__((ext_vector_type(8)));
typedef float f32x4 __attribute__((ext_vector_type(4)));
typedef unsigned short us4 __attribute__((ext_vector_type(4)));
typedef unsigned short us8 __attribute__((ext_vector_type(8)));

__device__ __forceinline__ float bf2f(u16 x){
  union { unsigned int u; float f; } v; v.u = ((unsigned int)x) << 16; return v.f;
}
__device__ __forceinline__ u16 f2bf(float f){
  union { float f; unsigned int u; } v; v.f = f;
  unsigned int r = (v.u + 0x7fffu + ((v.u >> 16) & 1u)) >> 16; return (u16)r;
}

#define AS1 __attribute__((address_space(1)))
#define AS3 __attribute__((address_space(3)))
__device__ __forceinline__ void gld_lds16(const void* g, void* l){
  __builtin_amdgcn_global_load_lds((const AS1 void*)g, (AS3 void*)l, 16, 0, 0);
}

// ---------------- embedding ----------------
__global__ void k_embed(const int* __restrict__ ids, const float* __restrict__ Wemb,
                        float* __restrict__ h, u16* __restrict__ hb){
  int bt = blockIdx.x; long id = ids[bt];
  const float4* src = (const float4*)(Wemb + id*(long)DIM);
  float4 v = src[threadIdx.x];
  ((float4*)(h + (long)bt*DIM))[threadIdx.x] = v;
  us4 o = { f2bf(v.x), f2bf(v.y), f2bf(v.z), f2bf(v.w) };
  ((us4*)(hb + (long)bt*DIM))[threadIdx.x] = o;
}

// ---------------- f32 -> bf16 elementwise (Wemb) ----------------
__global__ void k_cvt(const float* __restrict__ src, u16* __restrict__ dst, long n){
  long i = ((long)blockIdx.x*256 + threadIdx.x)*8;
  if (i >= n) return;
  float4 a = ((const float4*)(src+i))[0];
  float4 b = ((const float4*)(src+i))[1];
  us4 o0 = { f2bf(a.x), f2bf(a.y), f2bf(a.z), f2bf(a.w) };
  us4 o1 = { f2bf(b.x), f2bf(b.y), f2bf(b.z), f2bf(b.w) };
  ((us4*)(dst+i))[0] = o0; ((us4*)(dst+i))[1] = o1;
}

// ---------------- per-layer weight convert + transpose (coalesced both sides) ----------------
__global__ void k_cvt_layer(const float* __restrict__ Wq, const float* __restrict__ Wk,
    const float* __restrict__ Wv, const float* __restrict__ Wo,
    const float* __restrict__ Wfc, const float* __restrict__ Wg, const float* __restrict__ Wp,
    u16* __restrict__ qkvT, u16* __restrict__ woT, u16* __restrict__ fgT, u16* __restrict__ projT)
{
  int tile = blockIdx.x;
  const float* src; u16* dst; int R, C, tr, tc;
  long rowmul = 1, rowoff = 0;
  if (tile < 1024){
    int m = tile >> 8, t2 = tile & 255;
    tr = t2 >> 4; tc = t2 & 15; R = 1024; C = 1024;
    src = (m==0)?Wq:(m==1)?Wk:(m==2)?Wv:Wo;
    dst = (m<3)? qkvT + (long)m*1024*1024 : woT;
  } else if (tile < 3072){
    int m = (tile - 1024) >> 10, t2 = (tile - 1024) & 1023;
    tr = t2 >> 6; tc = t2 & 63; R = 1024; C = 4096;
    src = m ? Wg : Wfc; dst = fgT; rowmul = 2; rowoff = m;
  } else {
    int t2 = tile - 3072;
    tr = t2 >> 4; tc = t2 & 15; R = 4096; C = 1024;
    src = Wp; dst = projT;
  }
  __shared__ float ls[64][65];
  int u = threadIdx.x;
  int rr16 = u >> 4;
  int cu   = u & 15;
  #pragma unroll
  for (int p = 0; p < 4; ++p){
    int r = p*16 + rr16;
    float4 v = *(const float4*)(src + (long)(tr*64 + r)*C + tc*64 + cu*4);
    ls[r][cu*4+0]=v.x; ls[r][cu*4+1]=v.y; ls[r][cu*4+2]=v.z; ls[r][cu*4+3]=v.w;
  }
  __syncthreads();
  int d  = u >> 2;
  int c4 = u & 3;
  long drow = (long)tc*64 + d;
  u16* dp = dst + (drow*rowmul + rowoff)*R + tr*64;
  #pragma unroll
  for (int g2 = 0; g2 < 2; ++g2){
    int e0 = (c4 + g2*4) * 8;
    us8 o;
    #pragma unroll
    for (int j=0;j<8;j++) o[j] = f2bf(ls[e0+j][d]);
    *((us8*)(dp + e0)) = o;
  }
}

// ============ 128-tile bf16 GEMM (qkv / wo-splitK / proj-splitK) ============
// EPI 0: store bf16   5: bf16 partial store (split-K)
template<int EPI>
__global__ __launch_bounds__(256, 2) void k_gemm(
    const u16* __restrict__ A, long lda,
    const u16* __restrict__ Bt, long ldb,
    void* __restrict__ Cp, long ldc,
    int K, int nMt, float alpha, int ksplit,
    u16* __restrict__ hbout)
{
  __shared__ u16 lsA[128*32];
  __shared__ u16 lsB[128*32];
  int nflat = gridDim.x; int w = blockIdx.x;
  if ((nflat & 7) == 0){ int q = nflat >> 3; w = (w & 7)*q + (w >> 3); }
  int perk = nflat / ksplit;
  int kc = w / perk; int w2 = w - kc*perk;
  int mtile = w2 % nMt, ntile = w2 / nMt;
  const u16* Ab = A + (long)mtile*128*lda + (long)kc*K;
  const u16* Bb = Bt + (long)ntile*128*ldb + (long)kc*K;
  int t = threadIdx.x;
  int wv = t >> 6, ln = t & 63;
  int srow = t >> 2;
  int scol = (t & 3) * 8;
  int fr = ln & 15, kg = ln >> 4;
  int wr = wv >> 1, wc = wv & 1;
  const f32x4 zero = {0.f,0.f,0.f,0.f};
  f32x4 acc[4][4];
  #pragma unroll
  for (int m=0;m<4;m++)
    #pragma unroll
    for (int n=0;n<4;n++) acc[m][n] = zero;
  const u16* ga0 = Ab + (long)srow*lda + scol;
  const u16* ga1 = Ab + (long)(srow+64)*lda + scol;
  const u16* gb0 = Bb + (long)srow*ldb + scol;
  const u16* gb1 = Bb + (long)(srow+64)*ldb + scol;
  u16* la0 = lsA + wv*512;
  u16* la1 = lsA + 2048 + wv*512;
  u16* lb0 = lsB + wv*512;
  u16* lb1 = lsB + 2048 + wv*512;
  for (int k0 = 0; k0 < K; k0 += 32){
    gld_lds16(ga0 + k0, la0);
    gld_lds16(ga1 + k0, la1);
    gld_lds16(gb0 + k0, lb0);
    gld_lds16(gb1 + k0, lb1);
    __syncthreads();
    short8 af[4], bfr[4];
    #pragma unroll
    for (int m=0;m<4;m++) af[m]  = *(const short8*)(lsA + (wr*64 + m*16 + fr)*32 + kg*8);
    #pragma unroll
    for (int n=0;n<4;n++) bfr[n] = *(const short8*)(lsB + (wc*64 + n*16 + fr)*32 + kg*8);
    #pragma unroll
    for (int m=0;m<4;m++)
      #pragma unroll
      for (int n=0;n<4;n++)
        acc[m][n] = __builtin_amdgcn_mfma_f32_16x16x32_bf16(af[m], bfr[n], acc[m][n], 0, 0, 0);
    __syncthreads();
  }
  long row0 = (long)mtile*128 + wr*64 + kg*4;
  int col0 = ntile*128 + wc*64 + fr;
  if constexpr (EPI == 0){
    u16* C = (u16*)Cp;
    #pragma unroll
    for (int m=0;m<4;m++)
      #pragma unroll
      for (int r=0;r<4;r++){
        long row = row0 + m*16 + r;
        #pragma unroll
        for (int n=0;n<4;n++) C[row*ldc + col0 + n*16] = f2bf(acc[m][n][r]);
      }
  } else { // EPI 5: bf16 partial store at [kc][row][col]
    u16* C = (u16*)Cp + (long)kc*MROWS*ldc;
    #pragma unroll
    for (int m=0;m<4;m++)
      #pragma unroll
      for (int r=0;r<4;r++){
        long row = row0 + m*16 + r;
        #pragma unroll
        for (int n=0;n<4;n++) C[row*ldc + col0 + n*16] = f2bf(acc[m][n][r]);
      }
  }
}

// ---------------- split-K reduce (NS bf16 partials) + residual ----------------
template<int NS>
__global__ void k_redKn(const u16* __restrict__ pK, float* __restrict__ h, u16* __restrict__ hb){
  long idx = ((long)blockIdx.x*256 + threadIdx.x)*4;
  const float aL = 0.35355339059327373f;
  float sx = 0.f, sy = 0.f, sz = 0.f, sw = 0.f;
  #pragma unroll
  for (int j=0;j<NS;j++){
    us4 p = *(const us4*)(pK + idx + (long)j*MROWS*1024);
    sx += bf2f(p[0]); sy += bf2f(p[1]); sz += bf2f(p[2]); sw += bf2f(p[3]);
  }
  float4 hv = *(const float4*)(h + idx);
  float4 v;
  v.x = hv.x + sx*aL;
  v.y = hv.y + sy*aL;
  v.z = hv.z + sz*aL;
  v.w = hv.w + sw*aL;
  *(float4*)(h + idx) = v;
  us4 o = { f2bf(v.x), f2bf(v.y), f2bf(v.z), f2bf(v.w) };
  *(us4*)(hb + idx) = o;
}

// ============ 256x256 8-wave BK=64 GEMM, 2-phase + register-reuse (fg / lm_head) ============
// NFAST=1: ntile-fastest within XCD chunk (A-panel L2-resident per XCD) — lm_head.
// NFAST=0: mtile-fastest (original) — fg.
#define MFMA_(va,vb,vc) __builtin_amdgcn_mfma_f32_16x16x32_bf16(va,vb,vc,0,0,0)
#define RD2(base, row, ku) (*(const short8*)((base) + (row)*64 + ((((ku) ^ ((row)&7)))<<3)))

template<int EPI, int NFAST>
__global__ __launch_bounds__(512, 1) void k_gemm256(
    const u16* __restrict__ A, long lda,
    const u16* __restrict__ Bt, long ldb,
    void* __restrict__ Cp, long ldc,
    int K, int nMt,
    float2* __restrict__ partials)
{
  __shared__ u16 lds[65536];   // [A0 32KB][B0 32KB][A1 32KB][B1 32KB]
  int nwg = gridDim.x; int w = blockIdx.x;
  { int q = nwg >> 3, r8 = nwg & 7; int xcd = w & 7, lw = w >> 3;
    w = (xcd < r8 ? xcd*(q+1) : r8*(q+1) + (xcd-r8)*q) + lw; }
  int mtile, ntile;
  if constexpr (NFAST){
    int nNt = nwg / nMt;
    ntile = w % nNt; mtile = w / nNt;
  } else {
    mtile = w % nMt; ntile = w / nMt;
  }
  const u16* Abase = A + (long)mtile*256*lda;
  const u16* Bbase = Bt + (long)ntile*256*ldb;
  int tid = threadIdx.x;
  int wid = tid >> 6, ln = tid & 63;
  int wm = wid >> 2, wn = wid & 3;
  int fr = ln & 15, kg = ln >> 4;

  f32x4 acc[8][4];
  #pragma unroll
  for (int a=0;a<8;a++)
    #pragma unroll
    for (int b=0;b<4;b++) acc[a][b] = (f32x4){0.f,0.f,0.f,0.f};

#define STAGE_A(i, kofs, dstbase) do{ \
    int u_ = (i)*512 + tid; int r_ = u_>>3; int cu_ = u_&7; \
    gld_lds16(Abase + (long)r_*lda + (kofs) + ((cu_^(r_&7))<<3), \
              (dstbase) + (((i)*512 + wid*64)<<3)); }while(0)
#define STAGE_B(i, kofs, dstbase) do{ \
    int u_ = (i)*512 + tid; int r_ = u_>>3; int cu_ = u_&7; \
    gld_lds16(Bbase + (long)r_*ldb + (kofs) + ((cu_^(r_&7))<<3), \
              (dstbase) + (((i)*512 + wid*64)<<3)); }while(0)

#define KHALF(ks) do{ \
    short8 a0 = RD2(ldsA, wm*128 +   0 + fr, (ks)*4+kg); \
    short8 a1 = RD2(ldsA, wm*128 +  16 + fr, (ks)*4+kg); \
    short8 a2 = RD2(ldsA, wm*128 +  32 + fr, (ks)*4+kg); \
    short8 a3 = RD2(ldsA, wm*128 +  48 + fr, (ks)*4+kg); \
    short8 a4 = RD2(ldsA, wm*128 +  64 + fr, (ks)*4+kg); \
    short8 a5 = RD2(ldsA, wm*128 +  80 + fr, (ks)*4+kg); \
    short8 a6 = RD2(ldsA, wm*128 +  96 + fr, (ks)*4+kg); \
    short8 a7 = RD2(ldsA, wm*128 + 112 + fr, (ks)*4+kg); \
    short8 b0 = RD2(ldsB, wn*64 +  0 + fr, (ks)*4+kg); \
    short8 b1 = RD2(ldsB, wn*64 + 16 + fr, (ks)*4+kg); \
    short8 b2 = RD2(ldsB, wn*64 + 32 + fr, (ks)*4+kg); \
    short8 b3 = RD2(ldsB, wn*64 + 48 + fr, (ks)*4+kg); \
    acc[0][0]=MFMA_(a0,b0,acc[0][0]); acc[1][0]=MFMA_(a1,b0,acc[1][0]); \
    acc[0][1]=MFMA_(a0,b1,acc[0][1]); acc[1][1]=MFMA_(a1,b1,acc[1][1]); \
    acc[2][0]=MFMA_(a2,b0,acc[2][0]); acc[3][0]=MFMA_(a3,b0,acc[3][0]); \
    acc[2][1]=MFMA_(a2,b1,acc[2][1]); acc[3][1]=MFMA_(a3,b1,acc[3][1]); \
    acc[0][2]=MFMA_(a0,b2,acc[0][2]); acc[1][2]=MFMA_(a1,b2,acc[1][2]); \
    acc[0][3]=MFMA_(a0,b3,acc[0][3]); acc[1][3]=MFMA_(a1,b3,acc[1][3]); \
    acc[2][2]=MFMA_(a2,b2,acc[2][2]); acc[3][2]=MFMA_(a3,b2,acc[3][2]); \
    acc[2][3]=MFMA_(a2,b3,acc[2][3]); acc[3][3]=MFMA_(a3,b3,acc[3][3]); \
    acc[4][0]=MFMA_(a4,b0,acc[4][0]); acc[5][0]=MFMA_(a5,b0,acc[5][0]); \
    acc[4][1]=MFMA_(a4,b1,acc[4][1]); acc[5][1]=MFMA_(a5,b1,acc[5][1]); \
    acc[6][0]=MFMA_(a6,b0,acc[6][0]); acc[7][0]=MFMA_(a7,b0,acc[7][0]); \
    acc[6][1]=MFMA_(a6,b1,acc[6][1]); acc[7][1]=MFMA_(a7,b1,acc[7][1]); \
    acc[4][2]=MFMA_(a4,b2,acc[4][2]); acc[5][2]=MFMA_(a5,b2,acc[5][2]); \
    acc[4][3]=MFMA_(a4,b3,acc[4][3]); acc[5][3]=MFMA_(a5,b3,acc[5][3]); \
    acc[6][2]=MFMA_(a6,b2,acc[6][2]); acc[7][2]=MFMA_(a7,b2,acc[7][2]); \
    acc[6][3]=MFMA_(a6,b3,acc[6][3]); acc[7][3]=MFMA_(a7,b3,acc[7][3]); \
  }while(0)

  // prologue: stage tile 0 into buffer 0
  {
    u16* dA = lds; u16* dB = lds + 16384;
    STAGE_A(0, 0, dA); STAGE_A(1, 0, dA); STAGE_A(2, 0, dA); STAGE_A(3, 0, dA);
    STAGE_B(0, 0, dB); STAGE_B(1, 0, dB); STAGE_B(2, 0, dB); STAGE_B(3, 0, dB);
  }
  const int NT = K >> 6;
  #pragma unroll 2
  for (int jt = 0; jt < NT; ++jt){
    int bsel = jt & 1;
    u16* ldsA = lds + bsel*32768;
    u16* ldsB = ldsA + 16384;
    u16* nA = lds + (bsel^1)*32768;
    u16* nB = nA + 16384;
    long k1 = (long)(jt+1) << 6;
    bool pref = (jt+1 < NT);
    if (pref){
      STAGE_A(0, k1, nA); STAGE_A(1, k1, nA);
      STAGE_B(0, k1, nB); STAGE_B(1, k1, nB);
      asm volatile("s_waitcnt vmcnt(4)" ::: "memory");
    } else {
      asm volatile("s_waitcnt vmcnt(0)" ::: "memory");
    }
    __builtin_amdgcn_s_barrier();
    __builtin_amdgcn_s_setprio(1);
    KHALF(0);
    __builtin_amdgcn_s_setprio(0);
    __builtin_amdgcn_sched_barrier(0);
    if (pref){
      STAGE_A(2, k1, nA); STAGE_A(3, k1, nA);
      STAGE_B(2, k1, nB); STAGE_B(3, k1, nB);
    }
    __builtin_amdgcn_sched_barrier(0);
    __builtin_amdgcn_s_setprio(1);
    KHALF(1);
    __builtin_amdgcn_s_setprio(0);
    __builtin_amdgcn_sched_barrier(0);
    __builtin_amdgcn_s_barrier();
  }

  if constexpr (EPI == 3){
    u16* act = (u16*)Cp;
    const float sc = 0.015625f;  // 1/sqrt(4096)
    #pragma unroll
    for (int a=0;a<8;a++){
      long rowb = (long)mtile*256 + wm*128 + a*16 + kg*4;
      #pragma unroll
      for (int r=0;r<4;r++){
        #pragma unroll
        for (int b=0;b<4;b++){
          float v = acc[a][b][r];
          float pv = __shfl_xor(v, 1);
          if (!(fr & 1)){
            int colg = ntile*256 + wn*64 + b*16 + fr;
            float g = pv;
            float sl = g / (1.0f + __expf(-g));
            act[(rowb+r)*ldc + (colg>>1)] = f2bf(v * sl * sc);
          }
        }
      }
    }
  } else { // EPI 4: f32 store + per-row LSE partials
    float* C = (float*)Cp;
    #pragma unroll
    for (int a=0;a<8;a++){
      long rowb = (long)mtile*256 + wm*128 + a*16 + kg*4;
      #pragma unroll
      for (int r=0;r<4;r++){
        #pragma unroll
        for (int b=0;b<4;b++){
          int colg = ntile*256 + wn*64 + b*16 + fr;
          C[(rowb+r)*ldc + colg] = acc[a][b][r];
        }
      }
    }
    float* pm = (float*)lds;          // [4][256]
    float* ps = pm + 1024;            // [4][256]
    #pragma unroll
    for (int a=0;a<8;a++)
      #pragma unroll
      for (int r=0;r<4;r++){
        float M = fmaxf(fmaxf(acc[a][0][r],acc[a][1][r]), fmaxf(acc[a][2][r],acc[a][3][r]));
        #pragma unroll
        for (int o=1;o<16;o<<=1) M = fmaxf(M, __shfl_xor(M, o));
        float S = __expf(acc[a][0][r]-M) + __expf(acc[a][1][r]-M)
                + __expf(acc[a][2][r]-M) + __expf(acc[a][3][r]-M);
        #pragma unroll
        for (int o=1;o<16;o<<=1) S += __shfl_xor(S, o);
        if (fr == 0){
          int rl = wm*128 + a*16 + kg*4 + r;
          pm[wn*256 + rl] = M; ps[wn*256 + rl] = S;
        }
      }
    __syncthreads();
    if (tid < 256){
      float m0 = pm[tid], m1 = pm[256+tid], m2 = pm[512+tid], m3 = pm[768+tid];
      float M = fmaxf(fmaxf(m0,m1), fmaxf(m2,m3));
      float S = ps[tid]*__expf(m0-M) + ps[256+tid]*__expf(m1-M)
              + ps[512+tid]*__expf(m2-M) + ps[768+tid]*__expf(m3-M);
      partials[((long)mtile*256 + tid)*128 + ntile] = make_float2(M, S);
    }
  }
#undef STAGE_A
#undef STAGE_B
#undef KHALF
}

// ---------------- transpose V -> vT[z][d][t'] (unit-swizzled within 128-tiles) ----------------
__global__ void k_transpose_v(const u16* __restrict__ qkv, u16* __restrict__ vT){
  int ttile = blockIdx.x; int z = blockIdx.y;
  long b = z >> 4; int hh = z & 15;
  const u16* v = qkv + b*TT*3072 + 2048 + hh*64;
  u16* outp = vT + (long)z*64*TT;
  __shared__ u16 ls[64][65];
  int u = threadIdx.x, rr = u & 63, cc = u >> 6;
  const u16* sp = v + (long)(ttile*64 + rr)*3072 + cc*16;
  us4 a0 = ((const us4*)sp)[0];
  us4 a1 = ((const us4*)sp)[1];
  us4 a2 = ((const us4*)sp)[2];
  us4 a3 = ((const us4*)sp)[3];
  #pragma unroll
  for (int j=0;j<4;j++){ ls[rr][cc*16+j] = a0[j]; ls[rr][cc*16+4+j] = a1[j];
                         ls[rr][cc*16+8+j] = a2[j]; ls[rr][cc*16+12+j] = a3[j]; }
  __syncthreads();
  int d = u & 63;
  #pragma unroll
  for (int g=0; g<4; ++g){
    int tl = cc*16 + g*4;
    int t  = ttile*64 + tl;
    int ut = (t >> 3) & 15;
    int tp = (t & ~127) + (((ut ^ (d & 15)) << 3) | (t & 7));
    us4 o = { ls[tl+0][d], ls[tl+1][d], ls[tl+2][d], ls[tl+3][d] };
    *((us4*)(outp + (long)d*TT + tp)) = o;
  }
}

// ---------------- fused flash attention (QBLK=32, 4 blocks/CU, lsP aliases lsK) ----------------
__global__ __launch_bounds__(128) void k_flash(
    const u16* __restrict__ qkv, const u16* __restrict__ vT, u16* __restrict__ attnb)
{
  __shared__ u16 lsQ[32*64];     // 4KB
  __shared__ u16 lsK[128*64];    // 16KB; first 8KB reused as P [32][128]
  __shared__ u16 lsV[64*128];    // 16KB
  u16* lsP = lsK;
  int id = blockIdx.x;
  int wq = id >> 5, z = id & 31;
  int qt = (wq < 16) ? wq : 47 - wq;
  long bT = (long)(z >> 4) * TT;
  int h64 = (z & 15) * 64;
  int t = threadIdx.x, wv = t >> 6, ln = t & 63;
  int fr = ln & 15, kg = ln >> 4;
  const u16* vbase = vT + (long)z*64*TT;

  #pragma unroll
  for (int p=0; p<2; ++p){
    int r = p*16 + wv*8 + (ln>>3);
    const u16* g = qkv + (bT + qt*32 + r)*3072 + h64 + (((ln&7) ^ (ln>>3))*8);
    gld_lds16(g, lsQ + (p*16 + wv*8)*64);
  }

  f32x4 S[8], O[4];
  float Mst[4], Lst[4];
  #pragma unroll
  for (int n=0;n<4;n++) O[n] = (f32x4){0.f,0.f,0.f,0.f};
  #pragma unroll
  for (int r=0;r<4;r++){ Mst[r] = -3.0e38f; Lst[r] = 0.f; }

  int nk = (qt >> 2) + 1;
  for (int kt = 0; kt < nk; ++kt){
    #pragma unroll
    for (int p=0; p<8; ++p){
      int r = p*16 + wv*8 + (ln>>3);
      const u16* g = qkv + (bT + kt*128 + r)*3072 + 1024 + h64 + (((ln&7) ^ (ln>>3))*8);
      gld_lds16(g, lsK + (p*16 + wv*8)*64);
    }
    #pragma unroll
    for (int p=0; p<8; ++p){
      int d = p*8 + wv*4 + (ln>>4);
      const u16* g = vbase + (long)d*TT + kt*128 + (ln&15)*8;
      gld_lds16(g, lsV + (p*8 + wv*4)*128);
    }
    __syncthreads();

    #pragma unroll
    for (int n=0;n<8;n++) S[n] = (f32x4){0.f,0.f,0.f,0.f};
    #pragma unroll
    for (int ks=0; ks<2; ++ks){
      int un = ((ks*4 + kg) ^ (fr & 7)) * 8;
      short8 a0 = *(const short8*)(lsQ + (wv*16 + fr)*64 + un);
      #pragma unroll
      for (int n=0;n<8;n++){
        short8 bb = *(const short8*)(lsK + (n*16 + fr)*64 + un);
        S[n] = __builtin_amdgcn_mfma_f32_16x16x32_bf16(a0, bb, S[n], 0,0,0);
      }
    }
    __syncthreads();   // all QK reads of lsK complete before P overwrites it

    #pragma unroll
    for (int r=0;r<4;r++){
      int rloc = wv*16 + kg*4 + r;
      int row_g = qt*32 + rloc;
      float x[8]; float mx = -3.0e38f;
      #pragma unroll
      for (int n=0;n<8;n++){
        int col_g = kt*128 + n*16 + fr;
        x[n] = (col_g <= row_g) ? S[n][r]*0.125f : -3.0e38f;
        mx = fmaxf(mx, x[n]);
      }
      #pragma unroll
      for (int o=1;o<16;o<<=1) mx = fmaxf(mx, __shfl_xor(mx, o));
      float Mnew = fmaxf(Mst[r], mx);
      float corr = __expf(Mst[r] - Mnew);
      Mst[r] = Mnew;
      float s = 0.f;
      #pragma unroll
      for (int n=0;n<8;n++){
        float p = __expf(x[n] - Mnew);
        s += p;
        int col = n*16 + fr;
        int col2 = ((((col>>3) ^ (rloc & 15)) << 3) | (col & 7));
        lsP[rloc*128 + col2] = f2bf(p);
      }
      #pragma unroll
      for (int o=1;o<16;o<<=1) s += __shfl_xor(s, o);
      Lst[r] = Lst[r]*corr + s;
      #pragma unroll
      for (int n=0;n<4;n++) O[n][r] *= corr;
    }

    #pragma unroll
    for (int ks=0; ks<4; ++ks){
      int up = ((ks*4 + kg) ^ fr) * 8;
      short8 p0 = *(const short8*)(lsP + (wv*16 + fr)*128 + up);
      #pragma unroll
      for (int n=0;n<4;n++){
        short8 vb = *(const short8*)(lsV + (n*16 + fr)*128 + up);
        O[n] = __builtin_amdgcn_mfma_f32_16x16x32_bf16(p0, vb, O[n], 0,0,0);
      }
    }
    __syncthreads();
  }

  #pragma unroll
  for (int r=0;r<4;r++){
    float inv = 1.0f / Lst[r];
    long row = bT + qt*32 + wv*16 + kg*4 + r;
    #pragma unroll
    for (int n=0;n<4;n++)
      attnb[row*1024 + h64 + n*16 + fr] = f2bf(O[n][r]*inv);
  }
}

// ---------------- NLL from partials ----------------
__global__ void k_nll2(const float2* __restrict__ part, const float* __restrict__ logits,
                       const int* __restrict__ labels, float* __restrict__ nll){
  int row = blockIdx.x; int ln = threadIdx.x;
  const float2* pr = part + (long)row*128;
  float m = -3.0e38f, s = 0.f;
  for (int j = ln; j < 125; j += 64){
    float2 p = pr[j];
    float M = fmaxf(m, p.x);
    s = s*__expf(m - M) + p.y*__expf(p.x - M);
    m = M;
  }
  #pragma unroll
  for (int o=32;o;o>>=1){
    float om = __shfl_xor(m, o), os = __shfl_xor(s, o);
    float M = fmaxf(m, om);
    s = s*__expf(m - M) + os*__expf(om - M);
    m = M;
  }
  if (ln == 0){
    int lab = labels[row];
    float lse = m + __logf(s);
    nll[row] = (lab != -1) ? (lse - logits[(long)row*VOCAB + lab]) : 0.f;
  }
}

__global__ void k_loss(const float* __restrict__ nll, const int* __restrict__ labels,
                       float* __restrict__ out){
  int tid = threadIdx.x;
  int wv = tid >> 6;
  float s = 0.f; float c = 0.f;
  for (int i = tid; i < MROWS; i += 256){
    s += nll[i];
    c += (labels[i] != -1) ? 1.f : 0.f;
  }
  #pragma unroll
  for (int o=32;o;o>>=1){ s += __shfl_xor(s, o); c += __shfl_xor(c, o); }
  __shared__ float rsm[4], rc[4];
  if ((tid & 63) == 0){ rsm[wv] = s; rc[wv] = c; }
  __syncthreads();
  if (tid == 0){
    s = rsm[0]+rsm[1]+rsm[2]+rsm[3];
    c = rc[0]+rc[1]+rc[2]+rc[3];
    out[(long)MROWS*VOCAB] = s / fmaxf(c, 1.f);
  }
}

extern "C" void kernel_launch(void* const* d_in, const int* in_sizes, int n_in,
                              void* d_out, int out_size, void* d_ws, size_t ws_size,
                              hipStream_t stream)
{
  (void)in_sizes; (void)n_in; (void)out_size; (void)ws_size;
  const int*   ids    = (const int*)d_in[0];
  const int*   labels = (const int*)d_in[1];
  const float* Wemb   = (const float*)d_in[2];
  const float* Wq     = (const float*)d_in[3];
  const float* Wk     = (const float*)d_in[4];
  const float* Wv     = (const float*)d_in[5];
  const float* Wo     = (const float*)d_in[6];
  const float* Wfc    = (const float*)d_in[7];
  const float* Wg     = (const float*)d_in[8];
  const float* Wp     = (const float*)d_in[9];
  float* logits = (float*)d_out;

  char* ws = (char*)d_ws;
  size_t off = 0;
  auto alloc = [&](size_t bytes){ void* p = ws + off; off += (bytes + 255) & ~(size_t)255; return p; };
  u16*    wembBf = (u16*)alloc((size_t)VOCAB*DIM*2);
  float*  h      = (float*)alloc((size_t)MROWS*DIM*4);
  u16*    hb     = (u16*)alloc((size_t)MROWS*DIM*2);
  u16*    qkvT   = (u16*)alloc((size_t)3*DIM*DIM*2);
  u16*    woT    = (u16*)alloc((size_t)DIM*DIM*2);
  u16*    fgT    = (u16*)alloc((size_t)2*HID*DIM*2);
  u16*    projT  = (u16*)alloc((size_t)DIM*HID*2);
  u16*    qkv    = (u16*)alloc((size_t)MROWS*3*DIM*2);
  u16*    vT     = (u16*)alloc((size_t)BB*NH*64*TT*2);
  u16*    attnb  = (u16*)alloc((size_t)MROWS*DIM*2);
  u16*    act    = (u16*)alloc((size_t)MROWS*HID*2);
  u16*    pK     = (u16*)alloc((size_t)4*MROWS*DIM*2);
  float2* parts  = (float2*)alloc((size_t)MROWS*128*8);
  float*  nllb   = (float*)alloc((size_t)MROWS*4);

  dim3 blk(256,1,1);
  dim3 blk512(512,1,1);
  const float aL = 0.35355339059327373f;   // 1/sqrt(L)

  k_cvt<<<dim3(16000,1,1),blk,0,stream>>>(Wemb, wembBf, (long)VOCAB*DIM);
  k_embed<<<dim3(MROWS,1,1),blk,0,stream>>>(ids, Wemb, h, hb);

  for (int l = 0; l < L_LAYERS; ++l){
    k_cvt_layer<<<dim3(4096,1,1),blk,0,stream>>>(
        Wq + (size_t)l*DIM*DIM, Wk + (size_t)l*DIM*DIM, Wv + (size_t)l*DIM*DIM, Wo + (size_t)l*DIM*DIM,
        Wfc + (size_t)l*DIM*HID, Wg + (size_t)l*DIM*HID, Wp + (size_t)l*HID*DIM,
        qkvT, woT, fgT, projT);
    // QKV: [2048,1024] x [3072,1024]^T -> qkv bf16
    k_gemm<0><<<dim3(384,1,1),blk,0,stream>>>(hb,1024, qkvT,1024, qkv,3072,
        1024,16,1.f,1, nullptr);
    k_transpose_v<<<dim3(16,32,1),blk,0,stream>>>(qkv, vT);
    // fused flash attention (QBLK=32, 1024 blocks)
    k_flash<<<dim3(1024,1,1),dim3(128,1,1),0,stream>>>(qkv, vT, attnb);
    // Wo split-K x4 -> bf16 partials, reduce + residual
    k_gemm<5><<<dim3(512,1,1),blk,0,stream>>>(attnb,1024, woT,1024, pK,1024,
        256,16,1.f,4, nullptr);
    k_redKn<4><<<dim3(2048,1,1),blk,0,stream>>>(pK, h, hb);
    // fc|gate interleaved + fused SwiGLU -> act  (256^2 dbuf, m-fastest)
    k_gemm256<3,0><<<dim3(256,1,1),blk512,0,stream>>>(hb,1024, fgT,1024, act,4096,
        1024,8, nullptr);
    // proj split-K x4 -> bf16 partials, reduce + residual
    k_gemm<5><<<dim3(512,1,1),blk,0,stream>>>(act,4096, projT,4096, pK,1024,
        1024,16,1.f,4, nullptr);
    k_redKn<4><<<dim3(2048,1,1),blk,0,stream>>>(pK, h, hb);
  }
  // lm head (256^2 dbuf, XCD-resident A / n-fastest) + NLL partials
  k_gemm256<4,1><<<dim3(1000,1,1),blk512,0,stream>>>(hb,1024, wembBf,1024, logits,32000,
      1024,8, parts);
  k_nll2<<<dim3(MROWS,1,1),dim3(64,1,1),0,stream>>>(parts, logits, labels, nllb);
  k_loss<<<dim3(1,1,1),blk,0,stream>>>(nllb, labels, logits);
}

// Round 17
// 1622.897 us; speedup vs baseline: 1.0557x; 1.0144x over previous
//
#include <hip/hip_runtime.h>
#include <hip/hip_bf16.h>
#include <math.h>

#define L_LAYERS 8
#define DIM 1024
#define NH 16
#define HD 64
#define HID 4096
#define VOCAB 32000
#define BB 2
#define TT 1024
#define MROWS (BB*TT)

typedef unsigned short u16;
typedef short short8 __attribute__((ext_vector_type(8)));
typedef float f32x4 __attribute__((ext_vector_type(4)));
typedef unsigned short us4 __attribute__((ext_vector_type(4)));
typedef unsigned short us8 __attribute__((ext_vector_type(8)));

__device__ __forceinline__ float bf2f(u16 x){
  union { unsigned int u; float f; } v; v.u = ((unsigned int)x) << 16; return v.f;
}
__device__ __forceinline__ u16 f2bf(float f){
  union { float f; unsigned int u; } v; v.f = f;
  unsigned int r = (v.u + 0x7fffu + ((v.u >> 16) & 1u)) >> 16; return (u16)r;
}

#define AS1 __attribute__((address_space(1)))
#define AS3 __attribute__((address_space(3)))
__device__ __forceinline__ void gld_lds16(const void* g, void* l){
  __builtin_amdgcn_global_load_lds((const AS1 void*)g, (AS3 void*)l, 16, 0, 0);
}

// ---------------- embedding (bf16 residual stream) ----------------
__global__ void k_embed(const int* __restrict__ ids, const float* __restrict__ Wemb,
                        u16* __restrict__ hb){
  int bt = blockIdx.x; long id = ids[bt];
  const float4* src = (const float4*)(Wemb + id*(long)DIM);
  float4 v = src[threadIdx.x];
  us4 o = { f2bf(v.x), f2bf(v.y), f2bf(v.z), f2bf(v.w) };
  ((us4*)(hb + (long)bt*DIM))[threadIdx.x] = o;
}

// ---------------- f32 -> bf16 elementwise (Wemb) ----------------
__global__ void k_cvt(const float* __restrict__ src, u16* __restrict__ dst, long n){
  long i = ((long)blockIdx.x*256 + threadIdx.x)*8;
  if (i >= n) return;
  float4 a = ((const float4*)(src+i))[0];
  float4 b = ((const float4*)(src+i))[1];
  us4 o0 = { f2bf(a.x), f2bf(a.y), f2bf(a.z), f2bf(a.w) };
  us4 o1 = { f2bf(b.x), f2bf(b.y), f2bf(b.z), f2bf(b.w) };
  ((us4*)(dst+i))[0] = o0; ((us4*)(dst+i))[1] = o1;
}

// ---------------- per-layer weight convert + transpose (coalesced both sides) ----------------
__global__ void k_cvt_layer(const float* __restrict__ Wq, const float* __restrict__ Wk,
    const float* __restrict__ Wv, const float* __restrict__ Wo,
    const float* __restrict__ Wfc, const float* __restrict__ Wg, const float* __restrict__ Wp,
    u16* __restrict__ qkvT, u16* __restrict__ woT, u16* __restrict__ fgT, u16* __restrict__ projT)
{
  int tile = blockIdx.x;
  const float* src; u16* dst; int R, C, tr, tc;
  long rowmul = 1, rowoff = 0;
  if (tile < 1024){
    int m = tile >> 8, t2 = tile & 255;
    tr = t2 >> 4; tc = t2 & 15; R = 1024; C = 1024;
    src = (m==0)?Wq:(m==1)?Wk:(m==2)?Wv:Wo;
    dst = (m<3)? qkvT + (long)m*1024*1024 : woT;
  } else if (tile < 3072){
    int m = (tile - 1024) >> 10, t2 = (tile - 1024) & 1023;
    tr = t2 >> 6; tc = t2 & 63; R = 1024; C = 4096;
    src = m ? Wg : Wfc; dst = fgT; rowmul = 2; rowoff = m;
  } else {
    int t2 = tile - 3072;
    tr = t2 >> 4; tc = t2 & 15; R = 4096; C = 1024;
    src = Wp; dst = projT;
  }
  __shared__ float ls[64][65];
  int u = threadIdx.x;
  int rr16 = u >> 4;
  int cu   = u & 15;
  #pragma unroll
  for (int p = 0; p < 4; ++p){
    int r = p*16 + rr16;
    float4 v = *(const float4*)(src + (long)(tr*64 + r)*C + tc*64 + cu*4);
    ls[r][cu*4+0]=v.x; ls[r][cu*4+1]=v.y; ls[r][cu*4+2]=v.z; ls[r][cu*4+3]=v.w;
  }
  __syncthreads();
  int d  = u >> 2;
  int c4 = u & 3;
  long drow = (long)tc*64 + d;
  u16* dp = dst + (drow*rowmul + rowoff)*R + tr*64;
  #pragma unroll
  for (int g2 = 0; g2 < 2; ++g2){
    int e0 = (c4 + g2*4) * 8;
    us8 o;
    #pragma unroll
    for (int j=0;j<8;j++) o[j] = f2bf(ls[e0+j][d]);
    *((us8*)(dp + e0)) = o;
  }
}

// ============ 128-tile bf16 GEMM (qkv / wo-splitK / proj-splitK) ============
// EPI 0: store bf16   5: bf16 partial store (split-K)
template<int EPI>
__global__ __launch_bounds__(256, 2) void k_gemm(
    const u16* __restrict__ A, long lda,
    const u16* __restrict__ Bt, long ldb,
    void* __restrict__ Cp, long ldc,
    int K, int nMt, float alpha, int ksplit,
    u16* __restrict__ hbout)
{
  __shared__ u16 lsA[128*32];
  __shared__ u16 lsB[128*32];
  int nflat = gridDim.x; int w = blockIdx.x;
  if ((nflat & 7) == 0){ int q = nflat >> 3; w = (w & 7)*q + (w >> 3); }
  int perk = nflat / ksplit;
  int kc = w / perk; int w2 = w - kc*perk;
  int mtile = w2 % nMt, ntile = w2 / nMt;
  const u16* Ab = A + (long)mtile*128*lda + (long)kc*K;
  const u16* Bb = Bt + (long)ntile*128*ldb + (long)kc*K;
  int t = threadIdx.x;
  int wv = t >> 6, ln = t & 63;
  int srow = t >> 2;
  int scol = (t & 3) * 8;
  int fr = ln & 15, kg = ln >> 4;
  int wr = wv >> 1, wc = wv & 1;
  const f32x4 zero = {0.f,0.f,0.f,0.f};
  f32x4 acc[4][4];
  #pragma unroll
  for (int m=0;m<4;m++)
    #pragma unroll
    for (int n=0;n<4;n++) acc[m][n] = zero;
  const u16* ga0 = Ab + (long)srow*lda + scol;
  const u16* ga1 = Ab + (long)(srow+64)*lda + scol;
  const u16* gb0 = Bb + (long)srow*ldb + scol;
  const u16* gb1 = Bb + (long)(srow+64)*ldb + scol;
  u16* la0 = lsA + wv*512;
  u16* la1 = lsA + 2048 + wv*512;
  u16* lb0 = lsB + wv*512;
  u16* lb1 = lsB + 2048 + wv*512;
  for (int k0 = 0; k0 < K; k0 += 32){
    gld_lds16(ga0 + k0, la0);
    gld_lds16(ga1 + k0, la1);
    gld_lds16(gb0 + k0, lb0);
    gld_lds16(gb1 + k0, lb1);
    __syncthreads();
    short8 af[4], bfr[4];
    #pragma unroll
    for (int m=0;m<4;m++) af[m]  = *(const short8*)(lsA + (wr*64 + m*16 + fr)*32 + kg*8);
    #pragma unroll
    for (int n=0;n<4;n++) bfr[n] = *(const short8*)(lsB + (wc*64 + n*16 + fr)*32 + kg*8);
    #pragma unroll
    for (int m=0;m<4;m++)
      #pragma unroll
      for (int n=0;n<4;n++)
        acc[m][n] = __builtin_amdgcn_mfma_f32_16x16x32_bf16(af[m], bfr[n], acc[m][n], 0, 0, 0);
    __syncthreads();
  }
  long row0 = (long)mtile*128 + wr*64 + kg*4;
  int col0 = ntile*128 + wc*64 + fr;
  if constexpr (EPI == 0){
    u16* C = (u16*)Cp;
    #pragma unroll
    for (int m=0;m<4;m++)
      #pragma unroll
      for (int r=0;r<4;r++){
        long row = row0 + m*16 + r;
        #pragma unroll
        for (int n=0;n<4;n++) C[row*ldc + col0 + n*16] = f2bf(acc[m][n][r]);
      }
  } else { // EPI 5: bf16 partial store at [kc][row][col]
    u16* C = (u16*)Cp + (long)kc*MROWS*ldc;
    #pragma unroll
    for (int m=0;m<4;m++)
      #pragma unroll
      for (int r=0;r<4;r++){
        long row = row0 + m*16 + r;
        #pragma unroll
        for (int n=0;n<4;n++) C[row*ldc + col0 + n*16] = f2bf(acc[m][n][r]);
      }
  }
}

// ---------------- split-K reduce (NS bf16 partials) + bf16 residual RMW ----------------
template<int NS>
__global__ void k_redKn(const u16* __restrict__ pK, u16* __restrict__ hb){
  long idx = ((long)blockIdx.x*256 + threadIdx.x)*4;
  const float aL = 0.35355339059327373f;
  float sx = 0.f, sy = 0.f, sz = 0.f, sw = 0.f;
  #pragma unroll
  for (int j=0;j<NS;j++){
    us4 p = *(const us4*)(pK + idx + (long)j*MROWS*1024);
    sx += bf2f(p[0]); sy += bf2f(p[1]); sz += bf2f(p[2]); sw += bf2f(p[3]);
  }
  us4 hv = *(const us4*)(hb + idx);
  us4 o = { f2bf(bf2f(hv[0]) + sx*aL), f2bf(bf2f(hv[1]) + sy*aL),
            f2bf(bf2f(hv[2]) + sz*aL), f2bf(bf2f(hv[3]) + sw*aL) };
  *(us4*)(hb + idx) = o;
}

// ============ 256x256 8-wave BK=64 GEMM, 2-phase + register-reuse (fg / lm_head) ============
// NFAST=1: ntile-fastest within XCD chunk (A-panel L2-resident per XCD) — lm_head.
// NFAST=0: mtile-fastest (original) — fg.
#define MFMA_(va,vb,vc) __builtin_amdgcn_mfma_f32_16x16x32_bf16(va,vb,vc,0,0,0)
#define RD2(base, row, ku) (*(const short8*)((base) + (row)*64 + ((((ku) ^ ((row)&7)))<<3)))

template<int EPI, int NFAST>
__global__ __launch_bounds__(512, 1) void k_gemm256(
    const u16* __restrict__ A, long lda,
    const u16* __restrict__ Bt, long ldb,
    void* __restrict__ Cp, long ldc,
    int K, int nMt,
    float2* __restrict__ partials)
{
  __shared__ u16 lds[65536];   // [A0 32KB][B0 32KB][A1 32KB][B1 32KB]
  int nwg = gridDim.x; int w = blockIdx.x;
  { int q = nwg >> 3, r8 = nwg & 7; int xcd = w & 7, lw = w >> 3;
    w = (xcd < r8 ? xcd*(q+1) : r8*(q+1) + (xcd-r8)*q) + lw; }
  int mtile, ntile;
  if constexpr (NFAST){
    int nNt = nwg / nMt;
    ntile = w % nNt; mtile = w / nNt;
  } else {
    mtile = w % nMt; ntile = w / nMt;
  }
  const u16* Abase = A + (long)mtile*256*lda;
  const u16* Bbase = Bt + (long)ntile*256*ldb;
  int tid = threadIdx.x;
  int wid = tid >> 6, ln = tid & 63;
  int wm = wid >> 2, wn = wid & 3;
  int fr = ln & 15, kg = ln >> 4;

  f32x4 acc[8][4];
  #pragma unroll
  for (int a=0;a<8;a++)
    #pragma unroll
    for (int b=0;b<4;b++) acc[a][b] = (f32x4){0.f,0.f,0.f,0.f};

#define STAGE_A(i, kofs, dstbase) do{ \
    int u_ = (i)*512 + tid; int r_ = u_>>3; int cu_ = u_&7; \
    gld_lds16(Abase + (long)r_*lda + (kofs) + ((cu_^(r_&7))<<3), \
              (dstbase) + (((i)*512 + wid*64)<<3)); }while(0)
#define STAGE_B(i, kofs, dstbase) do{ \
    int u_ = (i)*512 + tid; int r_ = u_>>3; int cu_ = u_&7; \
    gld_lds16(Bbase + (long)r_*ldb + (kofs) + ((cu_^(r_&7))<<3), \
              (dstbase) + (((i)*512 + wid*64)<<3)); }while(0)

#define KHALF(ks) do{ \
    short8 a0 = RD2(ldsA, wm*128 +   0 + fr, (ks)*4+kg); \
    short8 a1 = RD2(ldsA, wm*128 +  16 + fr, (ks)*4+kg); \
    short8 a2 = RD2(ldsA, wm*128 +  32 + fr, (ks)*4+kg); \
    short8 a3 = RD2(ldsA, wm*128 +  48 + fr, (ks)*4+kg); \
    short8 a4 = RD2(ldsA, wm*128 +  64 + fr, (ks)*4+kg); \
    short8 a5 = RD2(ldsA, wm*128 +  80 + fr, (ks)*4+kg); \
    short8 a6 = RD2(ldsA, wm*128 +  96 + fr, (ks)*4+kg); \
    short8 a7 = RD2(ldsA, wm*128 + 112 + fr, (ks)*4+kg); \
    short8 b0 = RD2(ldsB, wn*64 +  0 + fr, (ks)*4+kg); \
    short8 b1 = RD2(ldsB, wn*64 + 16 + fr, (ks)*4+kg); \
    short8 b2 = RD2(ldsB, wn*64 + 32 + fr, (ks)*4+kg); \
    short8 b3 = RD2(ldsB, wn*64 + 48 + fr, (ks)*4+kg); \
    acc[0][0]=MFMA_(a0,b0,acc[0][0]); acc[1][0]=MFMA_(a1,b0,acc[1][0]); \
    acc[0][1]=MFMA_(a0,b1,acc[0][1]); acc[1][1]=MFMA_(a1,b1,acc[1][1]); \
    acc[2][0]=MFMA_(a2,b0,acc[2][0]); acc[3][0]=MFMA_(a3,b0,acc[3][0]); \
    acc[2][1]=MFMA_(a2,b1,acc[2][1]); acc[3][1]=MFMA_(a3,b1,acc[3][1]); \
    acc[0][2]=MFMA_(a0,b2,acc[0][2]); acc[1][2]=MFMA_(a1,b2,acc[1][2]); \
    acc[0][3]=MFMA_(a0,b3,acc[0][3]); acc[1][3]=MFMA_(a1,b3,acc[1][3]); \
    acc[2][2]=MFMA_(a2,b2,acc[2][2]); acc[3][2]=MFMA_(a3,b2,acc[3][2]); \
    acc[2][3]=MFMA_(a2,b3,acc[2][3]); acc[3][3]=MFMA_(a3,b3,acc[3][3]); \
    acc[4][0]=MFMA_(a4,b0,acc[4][0]); acc[5][0]=MFMA_(a5,b0,acc[5][0]); \
    acc[4][1]=MFMA_(a4,b1,acc[4][1]); acc[5][1]=MFMA_(a5,b1,acc[5][1]); \
    acc[6][0]=MFMA_(a6,b0,acc[6][0]); acc[7][0]=MFMA_(a7,b0,acc[7][0]); \
    acc[6][1]=MFMA_(a6,b1,acc[6][1]); acc[7][1]=MFMA_(a7,b1,acc[7][1]); \
    acc[4][2]=MFMA_(a4,b2,acc[4][2]); acc[5][2]=MFMA_(a5,b2,acc[5][2]); \
    acc[4][3]=MFMA_(a4,b3,acc[4][3]); acc[5][3]=MFMA_(a5,b3,acc[5][3]); \
    acc[6][2]=MFMA_(a6,b2,acc[6][2]); acc[7][2]=MFMA_(a7,b2,acc[7][2]); \
    acc[6][3]=MFMA_(a6,b3,acc[6][3]); acc[7][3]=MFMA_(a7,b3,acc[7][3]); \
  }while(0)

  // prologue: stage tile 0 into buffer 0
  {
    u16* dA = lds; u16* dB = lds + 16384;
    STAGE_A(0, 0, dA); STAGE_A(1, 0, dA); STAGE_A(2, 0, dA); STAGE_A(3, 0, dA);
    STAGE_B(0, 0, dB); STAGE_B(1, 0, dB); STAGE_B(2, 0, dB); STAGE_B(3, 0, dB);
  }
  const int NT = K >> 6;
  #pragma unroll 2
  for (int jt = 0; jt < NT; ++jt){
    int bsel = jt & 1;
    u16* ldsA = lds + bsel*32768;
    u16* ldsB = ldsA + 16384;
    u16* nA = lds + (bsel^1)*32768;
    u16* nB = nA + 16384;
    long k1 = (long)(jt+1) << 6;
    bool pref = (jt+1 < NT);
    if (pref){
      STAGE_A(0, k1, nA); STAGE_A(1, k1, nA);
      STAGE_B(0, k1, nB); STAGE_B(1, k1, nB);
      asm volatile("s_waitcnt vmcnt(4)" ::: "memory");
    } else {
      asm volatile("s_waitcnt vmcnt(0)" ::: "memory");
    }
    __builtin_amdgcn_s_barrier();
    __builtin_amdgcn_s_setprio(1);
    KHALF(0);
    __builtin_amdgcn_s_setprio(0);
    __builtin_amdgcn_sched_barrier(0);
    if (pref){
      STAGE_A(2, k1, nA); STAGE_A(3, k1, nA);
      STAGE_B(2, k1, nB); STAGE_B(3, k1, nB);
    }
    __builtin_amdgcn_sched_barrier(0);
    __builtin_amdgcn_s_setprio(1);
    KHALF(1);
    __builtin_amdgcn_s_setprio(0);
    __builtin_amdgcn_sched_barrier(0);
    __builtin_amdgcn_s_barrier();
  }

  if constexpr (EPI == 3){
    u16* act = (u16*)Cp;
    const float sc = 0.015625f;  // 1/sqrt(4096)
    #pragma unroll
    for (int a=0;a<8;a++){
      long rowb = (long)mtile*256 + wm*128 + a*16 + kg*4;
      #pragma unroll
      for (int r=0;r<4;r++){
        #pragma unroll
        for (int b=0;b<4;b++){
          float v = acc[a][b][r];
          float pv = __shfl_xor(v, 1);
          if (!(fr & 1)){
            int colg = ntile*256 + wn*64 + b*16 + fr;
            float g = pv;
            float sl = g / (1.0f + __expf(-g));
            act[(rowb+r)*ldc + (colg>>1)] = f2bf(v * sl * sc);
          }
        }
      }
    }
  } else { // EPI 4: f32 store + per-row LSE partials
    float* C = (float*)Cp;
    #pragma unroll
    for (int a=0;a<8;a++){
      long rowb = (long)mtile*256 + wm*128 + a*16 + kg*4;
      #pragma unroll
      for (int r=0;r<4;r++){
        #pragma unroll
        for (int b=0;b<4;b++){
          int colg = ntile*256 + wn*64 + b*16 + fr;
          C[(rowb+r)*ldc + colg] = acc[a][b][r];
        }
      }
    }
    float* pm = (float*)lds;          // [4][256]
    float* ps = pm + 1024;            // [4][256]
    #pragma unroll
    for (int a=0;a<8;a++)
      #pragma unroll
      for (int r=0;r<4;r++){
        float M = fmaxf(fmaxf(acc[a][0][r],acc[a][1][r]), fmaxf(acc[a][2][r],acc[a][3][r]));
        #pragma unroll
        for (int o=1;o<16;o<<=1) M = fmaxf(M, __shfl_xor(M, o));
        float S = __expf(acc[a][0][r]-M) + __expf(acc[a][1][r]-M)
                + __expf(acc[a][2][r]-M) + __expf(acc[a][3][r]-M);
        #pragma unroll
        for (int o=1;o<16;o<<=1) S += __shfl_xor(S, o);
        if (fr == 0){
          int rl = wm*128 + a*16 + kg*4 + r;
          pm[wn*256 + rl] = M; ps[wn*256 + rl] = S;
        }
      }
    __syncthreads();
    if (tid < 256){
      float m0 = pm[tid], m1 = pm[256+tid], m2 = pm[512+tid], m3 = pm[768+tid];
      float M = fmaxf(fmaxf(m0,m1), fmaxf(m2,m3));
      float S = ps[tid]*__expf(m0-M) + ps[256+tid]*__expf(m1-M)
              + ps[512+tid]*__expf(m2-M) + ps[768+tid]*__expf(m3-M);
      partials[((long)mtile*256 + tid)*128 + ntile] = make_float2(M, S);
    }
  }
#undef STAGE_A
#undef STAGE_B
#undef KHALF
}

// ---------------- transpose V -> vT[z][d][t'] (unit-swizzled within 128-tiles) ----------------
__global__ void k_transpose_v(const u16* __restrict__ qkv, u16* __restrict__ vT){
  int ttile = blockIdx.x; int z = blockIdx.y;
  long b = z >> 4; int hh = z & 15;
  const u16* v = qkv + b*TT*3072 + 2048 + hh*64;
  u16* outp = vT + (long)z*64*TT;
  __shared__ u16 ls[64][65];
  int u = threadIdx.x, rr = u & 63, cc = u >> 6;
  const u16* sp = v + (long)(ttile*64 + rr)*3072 + cc*16;
  us4 a0 = ((const us4*)sp)[0];
  us4 a1 = ((const us4*)sp)[1];
  us4 a2 = ((const us4*)sp)[2];
  us4 a3 = ((const us4*)sp)[3];
  #pragma unroll
  for (int j=0;j<4;j++){ ls[rr][cc*16+j] = a0[j]; ls[rr][cc*16+4+j] = a1[j];
                         ls[rr][cc*16+8+j] = a2[j]; ls[rr][cc*16+12+j] = a3[j]; }
  __syncthreads();
  int d = u & 63;
  #pragma unroll
  for (int g=0; g<4; ++g){
    int tl = cc*16 + g*4;
    int t  = ttile*64 + tl;
    int ut = (t >> 3) & 15;
    int tp = (t & ~127) + (((ut ^ (d & 15)) << 3) | (t & 7));
    us4 o = { ls[tl+0][d], ls[tl+1][d], ls[tl+2][d], ls[tl+3][d] };
    *((us4*)(outp + (long)d*TT + tp)) = o;
  }
}

// ---------------- fused flash attention (QBLK=32, 4 blocks/CU, lsP aliases lsK) ----------------
__global__ __launch_bounds__(128) void k_flash(
    const u16* __restrict__ qkv, const u16* __restrict__ vT, u16* __restrict__ attnb)
{
  __shared__ u16 lsQ[32*64];     // 4KB
  __shared__ u16 lsK[128*64];    // 16KB; first 8KB reused as P [32][128]
  __shared__ u16 lsV[64*128];    // 16KB
  u16* lsP = lsK;
  int id = blockIdx.x;
  int wq = id >> 5, z = id & 31;
  int qt = (wq < 16) ? wq : 47 - wq;
  long bT = (long)(z >> 4) * TT;
  int h64 = (z & 15) * 64;
  int t = threadIdx.x, wv = t >> 6, ln = t & 63;
  int fr = ln & 15, kg = ln >> 4;
  const u16* vbase = vT + (long)z*64*TT;

  #pragma unroll
  for (int p=0; p<2; ++p){
    int r = p*16 + wv*8 + (ln>>3);
    const u16* g = qkv + (bT + qt*32 + r)*3072 + h64 + (((ln&7) ^ (ln>>3))*8);
    gld_lds16(g, lsQ + (p*16 + wv*8)*64);
  }

  f32x4 S[8], O[4];
  float Mst[4], Lst[4];
  #pragma unroll
  for (int n=0;n<4;n++) O[n] = (f32x4){0.f,0.f,0.f,0.f};
  #pragma unroll
  for (int r=0;r<4;r++){ Mst[r] = -3.0e38f; Lst[r] = 0.f; }

  int nk = (qt >> 2) + 1;
  for (int kt = 0; kt < nk; ++kt){
    #pragma unroll
    for (int p=0; p<8; ++p){
      int r = p*16 + wv*8 + (ln>>3);
      const u16* g = qkv + (bT + kt*128 + r)*3072 + 1024 + h64 + (((ln&7) ^ (ln>>3))*8);
      gld_lds16(g, lsK + (p*16 + wv*8)*64);
    }
    #pragma unroll
    for (int p=0; p<8; ++p){
      int d = p*8 + wv*4 + (ln>>4);
      const u16* g = vbase + (long)d*TT + kt*128 + (ln&15)*8;
      gld_lds16(g, lsV + (p*8 + wv*4)*128);
    }
    __syncthreads();

    #pragma unroll
    for (int n=0;n<8;n++) S[n] = (f32x4){0.f,0.f,0.f,0.f};
    #pragma unroll
    for (int ks=0; ks<2; ++ks){
      int un = ((ks*4 + kg) ^ (fr & 7)) * 8;
      short8 a0 = *(const short8*)(lsQ + (wv*16 + fr)*64 + un);
      #pragma unroll
      for (int n=0;n<8;n++){
        short8 bb = *(const short8*)(lsK + (n*16 + fr)*64 + un);
        S[n] = __builtin_amdgcn_mfma_f32_16x16x32_bf16(a0, bb, S[n], 0,0,0);
      }
    }
    __syncthreads();   // all QK reads of lsK complete before P overwrites it

    #pragma unroll
    for (int r=0;r<4;r++){
      int rloc = wv*16 + kg*4 + r;
      int row_g = qt*32 + rloc;
      float x[8]; float mx = -3.0e38f;
      #pragma unroll
      for (int n=0;n<8;n++){
        int col_g = kt*128 + n*16 + fr;
        x[n] = (col_g <= row_g) ? S[n][r]*0.125f : -3.0e38f;
        mx = fmaxf(mx, x[n]);
      }
      #pragma unroll
      for (int o=1;o<16;o<<=1) mx = fmaxf(mx, __shfl_xor(mx, o));
      float Mnew = fmaxf(Mst[r], mx);
      float corr = __expf(Mst[r] - Mnew);
      Mst[r] = Mnew;
      float s = 0.f;
      #pragma unroll
      for (int n=0;n<8;n++){
        float p = __expf(x[n] - Mnew);
        s += p;
        int col = n*16 + fr;
        int col2 = ((((col>>3) ^ (rloc & 15)) << 3) | (col & 7));
        lsP[rloc*128 + col2] = f2bf(p);
      }
      #pragma unroll
      for (int o=1;o<16;o<<=1) s += __shfl_xor(s, o);
      Lst[r] = Lst[r]*corr + s;
      #pragma unroll
      for (int n=0;n<4;n++) O[n][r] *= corr;
    }

    #pragma unroll
    for (int ks=0; ks<4; ++ks){
      int up = ((ks*4 + kg) ^ fr) * 8;
      short8 p0 = *(const short8*)(lsP + (wv*16 + fr)*128 + up);
      #pragma unroll
      for (int n=0;n<4;n++){
        short8 vb = *(const short8*)(lsV + (n*16 + fr)*128 + up);
        O[n] = __builtin_amdgcn_mfma_f32_16x16x32_bf16(p0, vb, O[n], 0,0,0);
      }
    }
    __syncthreads();
  }

  #pragma unroll
  for (int r=0;r<4;r++){
    float inv = 1.0f / Lst[r];
    long row = bT + qt*32 + wv*16 + kg*4 + r;
    #pragma unroll
    for (int n=0;n<4;n++)
      attnb[row*1024 + h64 + n*16 + fr] = f2bf(O[n][r]*inv);
  }
}

// ---------------- NLL from partials ----------------
__global__ void k_nll2(const float2* __restrict__ part, const float* __restrict__ logits,
                       const int* __restrict__ labels, float* __restrict__ nll){
  int row = blockIdx.x; int ln = threadIdx.x;
  const float2* pr = part + (long)row*128;
  float m = -3.0e38f, s = 0.f;
  for (int j = ln; j < 125; j += 64){
    float2 p = pr[j];
    float M = fmaxf(m, p.x);
    s = s*__expf(m - M) + p.y*__expf(p.x - M);
    m = M;
  }
  #pragma unroll
  for (int o=32;o;o>>=1){
    float om = __shfl_xor(m, o), os = __shfl_xor(s, o);
    float M = fmaxf(m, om);
    s = s*__expf(m - M) + os*__expf(om - M);
    m = M;
  }
  if (ln == 0){
    int lab = labels[row];
    float lse = m + __logf(s);
    nll[row] = (lab != -1) ? (lse - logits[(long)row*VOCAB + lab]) : 0.f;
  }
}

__global__ void k_loss(const float* __restrict__ nll, const int* __restrict__ labels,
                       float* __restrict__ out){
  int tid = threadIdx.x;
  int wv = tid >> 6;
  float s = 0.f; float c = 0.f;
  for (int i = tid; i < MROWS; i += 256){
    s += nll[i];
    c += (labels[i] != -1) ? 1.f : 0.f;
  }
  #pragma unroll
  for (int o=32;o;o>>=1){ s += __shfl_xor(s, o); c += __shfl_xor(c, o); }
  __shared__ float rsm[4], rc[4];
  if ((tid & 63) == 0){ rsm[wv] = s; rc[wv] = c; }
  __syncthreads();
  if (tid == 0){
    s = rsm[0]+rsm[1]+rsm[2]+rsm[3];
    c = rc[0]+rc[1]+rc[2]+rc[3];
    out[(long)MROWS*VOCAB] = s / fmaxf(c, 1.f);
  }
}

extern "C" void kernel_launch(void* const* d_in, const int* in_sizes, int n_in,
                              void* d_out, int out_size, void* d_ws, size_t ws_size,
                              hipStream_t stream)
{
  (void)in_sizes; (void)n_in; (void)out_size; (void)ws_size;
  const int*   ids    = (const int*)d_in[0];
  const int*   labels = (const int*)d_in[1];
  const float* Wemb   = (const float*)d_in[2];
  const float* Wq     = (const float*)d_in[3];
  const float* Wk     = (const float*)d_in[4];
  const float* Wv     = (const float*)d_in[5];
  const float* Wo     = (const float*)d_in[6];
  const float* Wfc    = (const float*)d_in[7];
  const float* Wg     = (const float*)d_in[8];
  const float* Wp     = (const float*)d_in[9];
  float* logits = (float*)d_out;

  char* ws = (char*)d_ws;
  size_t off = 0;
  auto alloc = [&](size_t bytes){ void* p = ws + off; off += (bytes + 255) & ~(size_t)255; return p; };
  u16*    wembBf = (u16*)alloc((size_t)VOCAB*DIM*2);
  u16*    hb     = (u16*)alloc((size_t)MROWS*DIM*2);
  u16*    qkvT   = (u16*)alloc((size_t)3*DIM*DIM*2);
  u16*    woT    = (u16*)alloc((size_t)DIM*DIM*2);
  u16*    fgT    = (u16*)alloc((size_t)2*HID*DIM*2);
  u16*    projT  = (u16*)alloc((size_t)DIM*HID*2);
  u16*    qkv    = (u16*)alloc((size_t)MROWS*3*DIM*2);
  u16*    vT     = (u16*)alloc((size_t)BB*NH*64*TT*2);
  u16*    attnb  = (u16*)alloc((size_t)MROWS*DIM*2);
  u16*    act    = (u16*)alloc((size_t)MROWS*HID*2);
  u16*    pK     = (u16*)alloc((size_t)4*MROWS*DIM*2);
  float2* parts  = (float2*)alloc((size_t)MROWS*128*8);
  float*  nllb   = (float*)alloc((size_t)MROWS*4);

  dim3 blk(256,1,1);
  dim3 blk512(512,1,1);

  k_cvt<<<dim3(16000,1,1),blk,0,stream>>>(Wemb, wembBf, (long)VOCAB*DIM);
  k_embed<<<dim3(MROWS,1,1),blk,0,stream>>>(ids, Wemb, hb);

  for (int l = 0; l < L_LAYERS; ++l){
    k_cvt_layer<<<dim3(4096,1,1),blk,0,stream>>>(
        Wq + (size_t)l*DIM*DIM, Wk + (size_t)l*DIM*DIM, Wv + (size_t)l*DIM*DIM, Wo + (size_t)l*DIM*DIM,
        Wfc + (size_t)l*DIM*HID, Wg + (size_t)l*DIM*HID, Wp + (size_t)l*HID*DIM,
        qkvT, woT, fgT, projT);
    // QKV: [2048,1024] x [3072,1024]^T -> qkv bf16
    k_gemm<0><<<dim3(384,1,1),blk,0,stream>>>(hb,1024, qkvT,1024, qkv,3072,
        1024,16,1.f,1, nullptr);
    k_transpose_v<<<dim3(16,32,1),blk,0,stream>>>(qkv, vT);
    // fused flash attention (QBLK=32, 1024 blocks)
    k_flash<<<dim3(1024,1,1),dim3(128,1,1),0,stream>>>(qkv, vT, attnb);
    // Wo split-K x4 -> bf16 partials, reduce + bf16 residual
    k_gemm<5><<<dim3(512,1,1),blk,0,stream>>>(attnb,1024, woT,1024, pK,1024,
        256,16,1.f,4, nullptr);
    k_redKn<4><<<dim3(2048,1,1),blk,0,stream>>>(pK, hb);
    // fc|gate interleaved + fused SwiGLU -> act  (256^2 dbuf, m-fastest)
    k_gemm256<3,0><<<dim3(256,1,1),blk512,0,stream>>>(hb,1024, fgT,1024, act,4096,
        1024,8, nullptr);
    // proj split-K x4 -> bf16 partials, reduce + bf16 residual
    k_gemm<5><<<dim3(512,1,1),blk,0,stream>>>(act,4096, projT,4096, pK,1024,
        1024,16,1.f,4, nullptr);
    k_redKn<4><<<dim3(2048,1,1),blk,0,stream>>>(pK, hb);
  }
  // lm head (256^2 dbuf, XCD-resident A / n-fastest) + NLL partials
  k_gemm256<4,1><<<dim3(1000,1,1),blk512,0,stream>>>(hb,1024, wembBf,1024, logits,32000,
      1024,8, parts);
  k_nll2<<<dim3(MROWS,1,1),dim3(64,1,1),0,stream>>>(parts, logits, labels, nllb);
  k_loss<<<dim3(1,1,1),blk,0,stream>>>(nllb, labels, logits);
}